// Round 2
// baseline (4051.063 us; speedup 1.0000x reference)
//
#include <hip/hip_runtime.h>
#include <hip/hip_bf16.h>

#define EPSQ 1e-5f
// Problem sizes
#define B_ 2
#define S_ 1024
#define D_ 1024
#define E_ 2048
#define N_ 16
#define R_ 64

static __device__ __forceinline__ float block_sum(float v, float* red) {
  int t = threadIdx.x;
  red[t] = v;
  __syncthreads();
  #pragma unroll
  for (int off = 128; off > 0; off >>= 1) {
    if (t < off) red[t] += red[t + off];
    __syncthreads();
  }
  float r = red[0];
  __syncthreads();
  return r;
}

// ada = silu(c) @ Wada^T + bada   -> [B, 3D] fp32
// grid: B*3D blocks, 256 threads; one block per output element (K=2D=2048 dot)
__global__ void k_ada(const float* __restrict__ c, const float* __restrict__ Wada,
                      const float* __restrict__ bada, float* __restrict__ ada) {
  __shared__ float red[256];
  int j = blockIdx.x % (3 * D_);
  int b = blockIdx.x / (3 * D_);
  const float* crow = c + (size_t)b * (2 * D_);
  const float* wrow = Wada + (size_t)j * (2 * D_);
  float acc = 0.f;
  for (int i = threadIdx.x; i < 2 * D_; i += 256) {
    float cv = crow[i];
    float s = cv / (1.f + __expf(-cv));      // silu
    acc += s * wrow[i];
  }
  float tot = block_sum(acc, red);
  if (threadIdx.x == 0) ada[(size_t)b * (3 * D_) + j] = tot + bada[j];
}

// LN1 -> modulate(scale,shift) -> skip ; LN2 -> xs2.  One block per (b,s) row.
__global__ void k_ln(const float* __restrict__ x,
                     const float* __restrict__ g1, const float* __restrict__ b1,
                     const float* __restrict__ g2, const float* __restrict__ b2,
                     const float* __restrict__ ada,
                     float* __restrict__ skip, float* __restrict__ xs2) {
  __shared__ float red[256];
  int row = blockIdx.x;            // b*S + s
  int b = row >> 10;               // S = 1024
  int t = threadIdx.x;
  const float* xr = x + (size_t)row * D_;

  float v[4];
  float4 xv = *(const float4*)(xr + t * 4);
  v[0] = xv.x; v[1] = xv.y; v[2] = xv.z; v[3] = xv.w;

  float s = v[0] + v[1] + v[2] + v[3];
  float mean = block_sum(s, red) * (1.f / D_);
  float q = 0.f;
  #pragma unroll
  for (int i = 0; i < 4; ++i) { float d = v[i] - mean; q += d * d; }
  float var = block_sum(q, red) * (1.f / D_);
  float rstd = rsqrtf(var + EPSQ);

  const float* shf = ada + (size_t)b * (3 * D_);
  const float* scl = shf + D_;
  float s2 = 0.f;
  #pragma unroll
  for (int i = 0; i < 4; ++i) {
    int d = t * 4 + i;
    float xn = (v[i] - mean) * rstd * g1[d] + b1[d];
    float tt = xn * (1.f + scl[d]) + shf[d];
    v[i] = tt;
    s2 += tt;
    skip[(size_t)row * D_ + d] = tt;
  }
  float mean2 = block_sum(s2, red) * (1.f / D_);
  float q2 = 0.f;
  #pragma unroll
  for (int i = 0; i < 4; ++i) { float d = v[i] - mean2; q2 += d * d; }
  float var2 = block_sum(q2, red) * (1.f / D_);
  float rstd2 = rsqrtf(var2 + EPSQ);
  #pragma unroll
  for (int i = 0; i < 4; ++i) {
    int d = t * 4 + i;
    xs2[(size_t)row * D_ + d] = (v[i] - mean2) * rstd2 * g2[d] + b2[d];
  }
}

// Generic C[M,Nn] = A[M,K](f32, lda) @ W[Nn,K](f32)^T + bias
// EPI 0: store f32 ; EPI 1: silu then store f32 ;
// EPI 2: final out: o = x + gate*(v + skip), f32 store (Nn==D_)
template <int EPI>
__global__ void k_gemm(const float* __restrict__ A, int lda,
                       const float* __restrict__ W, const float* __restrict__ bias,
                       float* __restrict__ C, int M, int Nn, int K,
                       const float* __restrict__ skip, const float* __restrict__ xin,
                       const float* __restrict__ ada, float* __restrict__ obf) {
  const int BK = 16;
  __shared__ float As[BK][65];
  __shared__ float Bs[BK][65];
  int n0 = blockIdx.x * 64, m0 = blockIdx.y * 64;
  int t = threadIdx.x;
  int tx = t & 15, ty = t >> 4;
  int ar = t >> 2, ac4 = (t & 3) * 4;   // loader coords: row 0..63, k-chunk base
  float acc[4][4] = {};

  for (int k0 = 0; k0 < K; k0 += BK) {
    const float* ap = A + (size_t)(m0 + ar) * lda + k0 + ac4;
    float4 av = *(const float4*)ap;
    As[ac4 + 0][ar] = av.x; As[ac4 + 1][ar] = av.y;
    As[ac4 + 2][ar] = av.z; As[ac4 + 3][ar] = av.w;

    int wn = n0 + ar;
    if (wn < Nn) {
      const float* wp = W + (size_t)wn * K + k0 + ac4;
      float4 wv = *(const float4*)wp;
      Bs[ac4 + 0][ar] = wv.x; Bs[ac4 + 1][ar] = wv.y;
      Bs[ac4 + 2][ar] = wv.z; Bs[ac4 + 3][ar] = wv.w;
    } else {
      Bs[ac4 + 0][ar] = 0.f; Bs[ac4 + 1][ar] = 0.f;
      Bs[ac4 + 2][ar] = 0.f; Bs[ac4 + 3][ar] = 0.f;
    }
    __syncthreads();
    #pragma unroll
    for (int kk = 0; kk < BK; ++kk) {
      float a0 = As[kk][ty * 4 + 0], a1 = As[kk][ty * 4 + 1];
      float a2 = As[kk][ty * 4 + 2], a3 = As[kk][ty * 4 + 3];
      float c0 = Bs[kk][tx * 4 + 0], c1 = Bs[kk][tx * 4 + 1];
      float c2 = Bs[kk][tx * 4 + 2], c3 = Bs[kk][tx * 4 + 3];
      acc[0][0] += a0 * c0; acc[0][1] += a0 * c1; acc[0][2] += a0 * c2; acc[0][3] += a0 * c3;
      acc[1][0] += a1 * c0; acc[1][1] += a1 * c1; acc[1][2] += a1 * c2; acc[1][3] += a1 * c3;
      acc[2][0] += a2 * c0; acc[2][1] += a2 * c1; acc[2][2] += a2 * c2; acc[2][3] += a2 * c3;
      acc[3][0] += a3 * c0; acc[3][1] += a3 * c1; acc[3][2] += a3 * c2; acc[3][3] += a3 * c3;
    }
    __syncthreads();
  }

  #pragma unroll
  for (int i = 0; i < 4; ++i) {
    int row = m0 + ty * 4 + i;
    #pragma unroll
    for (int j = 0; j < 4; ++j) {
      int col = n0 + tx * 4 + j;
      if (col >= Nn) continue;
      float v = acc[i][j];
      if (bias) v += bias[col];
      if constexpr (EPI == 1) { v = v / (1.f + __expf(-v)); }
      if constexpr (EPI == 2) {
        int b = row >> 10;     // S=1024 rows per batch
        float gate = ada[(size_t)b * (3 * D_) + 2 * D_ + col];
        float o = v + skip[(size_t)row * D_ + col];
        obf[(size_t)row * D_ + col] = xin[(size_t)row * D_ + col] + gate * o;
      } else {
        C[(size_t)row * Nn + col] = v;
      }
    }
  }
}

// Selective scan. One thread per (b,e) channel, 16 states in registers.
// u (f32 [B,S,E]) is overwritten in place with the SSM output (+ u*Dp).
// dbc [B,S,96]: [0:64) dlt (unused here), [64:80) Bm, [80:96) Cm.
template <bool REV>
__global__ void k_scan(float* __restrict__ u, const float* __restrict__ dpre,
                       const float* __restrict__ dbc,
                       const float* __restrict__ Alog, const float* __restrict__ Dp) {
  int e = (blockIdx.x & 7) * 256 + threadIdx.x;   // E/256 = 8 chunks
  int b = blockIdx.x >> 3;
  float A[N_];
  #pragma unroll
  for (int n = 0; n < N_; ++n)
    A[n] = -__expf(Alog[(size_t)e * N_ + n]);
  float dp = Dp[e];
  float h[N_] = {};
  for (int si = 0; si < S_; ++si) {
    int s = REV ? (S_ - 1 - si) : si;
    size_t rowi = (size_t)b * S_ + s;
    size_t uix = rowi * E_ + e;
    float uu = u[uix];
    float dv = dpre[uix];
    float delta = (dv > 20.f) ? dv : log1pf(__expf(dv));   // softplus
    const float* bc = dbc + rowi * 96;
    float y = 0.f;
    #pragma unroll
    for (int n = 0; n < N_; ++n) {
      float dA = __expf(delta * A[n]);
      float Bm = bc[64 + n];
      float Cm = bc[80 + n];
      h[n] = dA * h[n] + delta * Bm * uu;
      y += h[n] * Cm;
    }
    u[uix] = y + uu * dp;
  }
}

// z1 <- actmx * (z1 + z2)
__global__ void k_ysum(float* __restrict__ z1, const float* __restrict__ z2,
                       const float* __restrict__ amx) {
  size_t i = (size_t)blockIdx.x * 256 + threadIdx.x;
  z1[i] = amx[i] * (z1[i] + z2[i]);
}

extern "C" void kernel_launch(void* const* d_in, const int* in_sizes, int n_in,
                              void* d_out, int out_size, void* d_ws, size_t ws_size,
                              hipStream_t stream) {
  const float* x     = (const float*)d_in[0];
  const float* c     = (const float*)d_in[1];
  const float* n1g   = (const float*)d_in[3];
  const float* n1b   = (const float*)d_in[4];
  const float* n2g   = (const float*)d_in[5];
  const float* n2b   = (const float*)d_in[6];
  const float* Wx    = (const float*)d_in[7];
  const float* bx    = (const float*)d_in[8];
  const float* Wz    = (const float*)d_in[9];
  const float* bz    = (const float*)d_in[10];
  const float* Wf    = (const float*)d_in[11];
  const float* bfb   = (const float*)d_in[12];
  const float* Wada  = (const float*)d_in[13];
  const float* bada  = (const float*)d_in[14];
  const float* Wc1   = (const float*)d_in[15];
  const float* bc1   = (const float*)d_in[16];
  const float* Wc2   = (const float*)d_in[17];
  const float* bc2   = (const float*)d_in[18];
  const float* Wdbc1 = (const float*)d_in[19];
  const float* Wdt1  = (const float*)d_in[20];
  const float* bdt1  = (const float*)d_in[21];
  const float* Alog1 = (const float*)d_in[22];
  const float* Dp1   = (const float*)d_in[23];
  const float* Wdbc2 = (const float*)d_in[24];
  const float* Wdt2  = (const float*)d_in[25];
  const float* bdt2  = (const float*)d_in[26];
  const float* Alog2 = (const float*)d_in[27];
  const float* Dp2   = (const float*)d_in[28];

  const int M = B_ * S_;                 // 2048
  float* ws   = (float*)d_ws;
  float* ada  = ws;                      // 6144 used, pad to 8192
  float* skip = ada + 8192;              // 2,097,152
  float* xs2  = skip + 2097152;          // 2,097,152 (reused as dbc later)
  float* mz   = xs2 + 2097152;           // 4,194,304 (reused as dlt later)
  float* amx  = mz + 4194304;            // 4,194,304
  float* z1   = amx + 4194304;           // 4,194,304
  float* z2   = z1 + 4194304;            // 4,194,304
  // aliases (dead buffers reused)
  float* dbc  = xs2;                     // needs 196,608 (xs2 dead after step 3)
  float* dlt  = mz;                      // needs 4,194,304 (mz dead after step 4)

  // 1. adaLN params
  k_ada<<<dim3(B_ * 3 * D_), dim3(256), 0, stream>>>(c, Wada, bada, ada);
  // 2. LN1 + modulate + LN2
  k_ln<<<dim3(M), dim3(256), 0, stream>>>(x, n1g, n1b, n2g, n2b, ada, skip, xs2);
  // 3. mz = xs2 @ Wz^T + bz ; actmx = silu(xs2 @ Wx^T + bx)
  k_gemm<0><<<dim3(E_ / 64, M / 64), 256, 0, stream>>>(xs2, D_, Wz, bz, mz, M, E_, D_,
                                                       nullptr, nullptr, nullptr, nullptr);
  k_gemm<1><<<dim3(E_ / 64, M / 64), 256, 0, stream>>>(xs2, D_, Wx, bx, amx, M, E_, D_,
                                                       nullptr, nullptr, nullptr, nullptr);
  // 4. z1 = mz @ Wc1^T + bc1 ; z2 = mz @ Wc2^T + bc2
  k_gemm<0><<<dim3(E_ / 64, M / 64), 256, 0, stream>>>(mz, E_, Wc1, bc1, z1, M, E_, E_,
                                                       nullptr, nullptr, nullptr, nullptr);
  k_gemm<0><<<dim3(E_ / 64, M / 64), 256, 0, stream>>>(mz, E_, Wc2, bc2, z2, M, E_, E_,
                                                       nullptr, nullptr, nullptr, nullptr);
  // 5. branch 1: dbc, delta_pre, forward scan (in-place on z1)
  k_gemm<0><<<dim3(2, M / 64), 256, 0, stream>>>(z1, E_, Wdbc1, nullptr, dbc, M, 96, E_,
                                                 nullptr, nullptr, nullptr, nullptr);
  k_gemm<0><<<dim3(E_ / 64, M / 64), 256, 0, stream>>>(dbc, 96, Wdt1, bdt1, dlt, M, E_, R_,
                                                       nullptr, nullptr, nullptr, nullptr);
  k_scan<false><<<dim3(B_ * (E_ / 256)), dim3(256), 0, stream>>>(z1, dlt, dbc, Alog1, Dp1);
  // 6. branch 2: dbc, delta_pre, reverse scan (in-place on z2; flips absorbed)
  k_gemm<0><<<dim3(2, M / 64), 256, 0, stream>>>(z2, E_, Wdbc2, nullptr, dbc, M, 96, E_,
                                                 nullptr, nullptr, nullptr, nullptr);
  k_gemm<0><<<dim3(E_ / 64, M / 64), 256, 0, stream>>>(dbc, 96, Wdt2, bdt2, dlt, M, E_, R_,
                                                       nullptr, nullptr, nullptr, nullptr);
  k_scan<true><<<dim3(B_ * (E_ / 256)), dim3(256), 0, stream>>>(z2, dlt, dbc, Alog2, Dp2);
  // 7. ysum = actmx*(z1+z2) -> z1
  k_ysum<<<dim3((M * E_) / 256), 256, 0, stream>>>(z1, z2, amx);
  // 8. out = ysum @ Wf^T + bf + skip ; d_out = x + gate*out  (f32)
  k_gemm<2><<<dim3(D_ / 64, M / 64), 256, 0, stream>>>(z1, E_, Wf, bfb, nullptr, M, D_, E_,
                                                       skip, x, ada, (float*)d_out);
}

// Round 3
// 1945.988 us; speedup vs baseline: 2.0818x; 2.0818x over previous
//
#include <hip/hip_runtime.h>
#include <hip/hip_bf16.h>

#define EPSQ 1e-5f
// Problem sizes
#define B_ 2
#define S_ 1024
#define D_ 1024
#define E_ 2048
#define N_ 16
#define R_ 64
// Chunked scan config
#define CS_ 64   // steps per chunk
#define NC_ 16   // chunks (CS_*NC_ == S_)
#define CH_ 4096 // channels = B_*E_

static __device__ __forceinline__ float block_sum(float v, float* red) {
  int t = threadIdx.x;
  red[t] = v;
  __syncthreads();
  #pragma unroll
  for (int off = 128; off > 0; off >>= 1) {
    if (t < off) red[t] += red[t + off];
    __syncthreads();
  }
  float r = red[0];
  __syncthreads();
  return r;
}

// ada = silu(c) @ Wada^T + bada   -> [B, 3D] fp32
__global__ void k_ada(const float* __restrict__ c, const float* __restrict__ Wada,
                      const float* __restrict__ bada, float* __restrict__ ada) {
  __shared__ float red[256];
  int j = blockIdx.x % (3 * D_);
  int b = blockIdx.x / (3 * D_);
  const float* crow = c + (size_t)b * (2 * D_);
  const float* wrow = Wada + (size_t)j * (2 * D_);
  float acc = 0.f;
  for (int i = threadIdx.x; i < 2 * D_; i += 256) {
    float cv = crow[i];
    float s = cv / (1.f + __expf(-cv));      // silu
    acc += s * wrow[i];
  }
  float tot = block_sum(acc, red);
  if (threadIdx.x == 0) ada[(size_t)b * (3 * D_) + j] = tot + bada[j];
}

// LN1 -> modulate(scale,shift) -> skip ; LN2 -> xs2.  One block per (b,s) row.
__global__ void k_ln(const float* __restrict__ x,
                     const float* __restrict__ g1, const float* __restrict__ b1,
                     const float* __restrict__ g2, const float* __restrict__ b2,
                     const float* __restrict__ ada,
                     float* __restrict__ skip, float* __restrict__ xs2) {
  __shared__ float red[256];
  int row = blockIdx.x;            // b*S + s
  int b = row >> 10;               // S = 1024
  int t = threadIdx.x;
  const float* xr = x + (size_t)row * D_;

  float v[4];
  float4 xv = *(const float4*)(xr + t * 4);
  v[0] = xv.x; v[1] = xv.y; v[2] = xv.z; v[3] = xv.w;

  float s = v[0] + v[1] + v[2] + v[3];
  float mean = block_sum(s, red) * (1.f / D_);
  float q = 0.f;
  #pragma unroll
  for (int i = 0; i < 4; ++i) { float d = v[i] - mean; q += d * d; }
  float var = block_sum(q, red) * (1.f / D_);
  float rstd = rsqrtf(var + EPSQ);

  const float* shf = ada + (size_t)b * (3 * D_);
  const float* scl = shf + D_;
  float s2 = 0.f;
  #pragma unroll
  for (int i = 0; i < 4; ++i) {
    int d = t * 4 + i;
    float xn = (v[i] - mean) * rstd * g1[d] + b1[d];
    float tt = xn * (1.f + scl[d]) + shf[d];
    v[i] = tt;
    s2 += tt;
    skip[(size_t)row * D_ + d] = tt;
  }
  float mean2 = block_sum(s2, red) * (1.f / D_);
  float q2 = 0.f;
  #pragma unroll
  for (int i = 0; i < 4; ++i) { float d = v[i] - mean2; q2 += d * d; }
  float var2 = block_sum(q2, red) * (1.f / D_);
  float rstd2 = rsqrtf(var2 + EPSQ);
  #pragma unroll
  for (int i = 0; i < 4; ++i) {
    int d = t * 4 + i;
    xs2[(size_t)row * D_ + d] = (v[i] - mean2) * rstd2 * g2[d] + b2[d];
  }
}

// Generic C[M,Nn] = A[M,K](f32, lda) @ W[Nn,K](f32)^T + bias
// EPI 0: store f32 ; EPI 1: silu then store f32 ;
// EPI 2: final out: o = x + gate*(v + skip), f32 store (Nn==D_)
template <int EPI>
__global__ void k_gemm(const float* __restrict__ A, int lda,
                       const float* __restrict__ W, const float* __restrict__ bias,
                       float* __restrict__ C, int M, int Nn, int K,
                       const float* __restrict__ skip, const float* __restrict__ xin,
                       const float* __restrict__ ada, float* __restrict__ obf) {
  const int BK = 16;
  __shared__ float As[BK][65];
  __shared__ float Bs[BK][65];
  int n0 = blockIdx.x * 64, m0 = blockIdx.y * 64;
  int t = threadIdx.x;
  int tx = t & 15, ty = t >> 4;
  int ar = t >> 2, ac4 = (t & 3) * 4;   // loader coords: row 0..63, k-chunk base
  float acc[4][4] = {};

  for (int k0 = 0; k0 < K; k0 += BK) {
    const float* ap = A + (size_t)(m0 + ar) * lda + k0 + ac4;
    float4 av = *(const float4*)ap;
    As[ac4 + 0][ar] = av.x; As[ac4 + 1][ar] = av.y;
    As[ac4 + 2][ar] = av.z; As[ac4 + 3][ar] = av.w;

    int wn = n0 + ar;
    if (wn < Nn) {
      const float* wp = W + (size_t)wn * K + k0 + ac4;
      float4 wv = *(const float4*)wp;
      Bs[ac4 + 0][ar] = wv.x; Bs[ac4 + 1][ar] = wv.y;
      Bs[ac4 + 2][ar] = wv.z; Bs[ac4 + 3][ar] = wv.w;
    } else {
      Bs[ac4 + 0][ar] = 0.f; Bs[ac4 + 1][ar] = 0.f;
      Bs[ac4 + 2][ar] = 0.f; Bs[ac4 + 3][ar] = 0.f;
    }
    __syncthreads();
    #pragma unroll
    for (int kk = 0; kk < BK; ++kk) {
      float a0 = As[kk][ty * 4 + 0], a1 = As[kk][ty * 4 + 1];
      float a2 = As[kk][ty * 4 + 2], a3 = As[kk][ty * 4 + 3];
      float c0 = Bs[kk][tx * 4 + 0], c1 = Bs[kk][tx * 4 + 1];
      float c2 = Bs[kk][tx * 4 + 2], c3 = Bs[kk][tx * 4 + 3];
      acc[0][0] += a0 * c0; acc[0][1] += a0 * c1; acc[0][2] += a0 * c2; acc[0][3] += a0 * c3;
      acc[1][0] += a1 * c0; acc[1][1] += a1 * c1; acc[1][2] += a1 * c2; acc[1][3] += a1 * c3;
      acc[2][0] += a2 * c0; acc[2][1] += a2 * c1; acc[2][2] += a2 * c2; acc[2][3] += a2 * c3;
      acc[3][0] += a3 * c0; acc[3][1] += a3 * c1; acc[3][2] += a3 * c2; acc[3][3] += a3 * c3;
    }
    __syncthreads();
  }

  #pragma unroll
  for (int i = 0; i < 4; ++i) {
    int row = m0 + ty * 4 + i;
    #pragma unroll
    for (int j = 0; j < 4; ++j) {
      int col = n0 + tx * 4 + j;
      if (col >= Nn) continue;
      float v = acc[i][j];
      if (bias) v += bias[col];
      if constexpr (EPI == 1) { v = v / (1.f + __expf(-v)); }
      if constexpr (EPI == 2) {
        int b = row >> 10;     // S=1024 rows per batch
        float gate = ada[(size_t)b * (3 * D_) + 2 * D_ + col];
        float o = v + skip[(size_t)row * D_ + col];
        obf[(size_t)row * D_ + col] = xin[(size_t)row * D_ + col] + gate * o;
      } else {
        C[(size_t)row * Nn + col] = v;
      }
    }
  }
}

static __device__ __forceinline__ float softplusf(float dv) {
  return (dv > 20.f) ? dv : log1pf(__expf(dv));
}

// ---- Chunked parallel scan (3 passes) ----
// Logical time tau = 0..S-1 ; physical s = REV ? S-1-tau : tau.
// Chunk c covers tau in [c*CS_, (c+1)*CS_).
// Summary layout: buf[(c*N_ + n)*CH_ + ch], ch = b*E_ + e.

// Pass A: per (ch, chunk): P[n] = prod dA, hl[n] = local state from h=0.
template <bool REV>
__global__ void k_scan_chunk(const float* __restrict__ u, const float* __restrict__ dlt,
                             const float* __restrict__ dbc, const float* __restrict__ Alog,
                             float* __restrict__ Pbuf, float* __restrict__ Hbuf) {
  int ch = (blockIdx.x & 15) * 256 + threadIdx.x;   // 0..4095
  int c  = blockIdx.x >> 4;                         // chunk 0..NC_-1
  int b = ch >> 11, e = ch & (E_ - 1);
  float A[N_], P[N_], h[N_];
  #pragma unroll
  for (int n = 0; n < N_; ++n) {
    A[n] = -__expf(Alog[(size_t)e * N_ + n]);
    P[n] = 1.f; h[n] = 0.f;
  }
  for (int t = 0; t < CS_; ++t) {
    int tau = c * CS_ + t;
    int s = REV ? (S_ - 1 - tau) : tau;
    size_t row = (size_t)b * S_ + s;
    float uu = u[row * E_ + e];
    float dv = dlt[row * E_ + e];
    float delta = softplusf(dv);
    float du = delta * uu;
    const float* bc = dbc + row * 96;
    #pragma unroll
    for (int n = 0; n < N_; ++n) {
      float dA = __expf(delta * A[n]);
      P[n] *= dA;
      h[n] = dA * h[n] + du * bc[64 + n];
    }
  }
  #pragma unroll
  for (int n = 0; n < N_; ++n) {
    size_t off = (size_t)(c * N_ + n) * CH_ + ch;
    Pbuf[off] = P[n];
    Hbuf[off] = h[n];
  }
}

// Pass B: per (ch, n): compose chunk summaries; overwrite Pbuf with chunk-initial state.
__global__ void k_scan_comb(float* __restrict__ Pbuf, const float* __restrict__ Hbuf) {
  int idx = blockIdx.x * 256 + threadIdx.x;   // 0..65535
  int ch = idx & (CH_ - 1);
  int n  = idx >> 12;
  float hcur = 0.f;
  for (int c = 0; c < NC_; ++c) {
    size_t off = (size_t)(c * N_ + n) * CH_ + ch;
    float p  = Pbuf[off];
    float hl = Hbuf[off];
    Pbuf[off] = hcur;           // initial state entering chunk c
    hcur = p * hcur + hl;
  }
}

// Pass C: per (ch, chunk): replay chunk from true initial state, emit y + u*Dp in place.
template <bool REV>
__global__ void k_scan_apply(float* __restrict__ u, const float* __restrict__ dlt,
                             const float* __restrict__ dbc, const float* __restrict__ Alog,
                             const float* __restrict__ Dp, const float* __restrict__ Pbuf) {
  int ch = (blockIdx.x & 15) * 256 + threadIdx.x;
  int c  = blockIdx.x >> 4;
  int b = ch >> 11, e = ch & (E_ - 1);
  float A[N_], h[N_];
  #pragma unroll
  for (int n = 0; n < N_; ++n) {
    A[n] = -__expf(Alog[(size_t)e * N_ + n]);
    h[n] = Pbuf[(size_t)(c * N_ + n) * CH_ + ch];
  }
  float dp = Dp[e];
  for (int t = 0; t < CS_; ++t) {
    int tau = c * CS_ + t;
    int s = REV ? (S_ - 1 - tau) : tau;
    size_t row = (size_t)b * S_ + s;
    float uu = u[row * E_ + e];
    float dv = dlt[row * E_ + e];
    float delta = softplusf(dv);
    float du = delta * uu;
    const float* bc = dbc + row * 96;
    float y = 0.f;
    #pragma unroll
    for (int n = 0; n < N_; ++n) {
      float dA = __expf(delta * A[n]);
      h[n] = dA * h[n] + du * bc[64 + n];
      y += h[n] * bc[80 + n];
    }
    u[row * E_ + e] = y + uu * dp;
  }
}

// z1 <- actmx * (z1 + z2)
__global__ void k_ysum(float* __restrict__ z1, const float* __restrict__ z2,
                       const float* __restrict__ amx) {
  size_t i = (size_t)blockIdx.x * 256 + threadIdx.x;
  z1[i] = amx[i] * (z1[i] + z2[i]);
}

extern "C" void kernel_launch(void* const* d_in, const int* in_sizes, int n_in,
                              void* d_out, int out_size, void* d_ws, size_t ws_size,
                              hipStream_t stream) {
  const float* x     = (const float*)d_in[0];
  const float* c     = (const float*)d_in[1];
  const float* n1g   = (const float*)d_in[3];
  const float* n1b   = (const float*)d_in[4];
  const float* n2g   = (const float*)d_in[5];
  const float* n2b   = (const float*)d_in[6];
  const float* Wx    = (const float*)d_in[7];
  const float* bx    = (const float*)d_in[8];
  const float* Wz    = (const float*)d_in[9];
  const float* bz    = (const float*)d_in[10];
  const float* Wf    = (const float*)d_in[11];
  const float* bfb   = (const float*)d_in[12];
  const float* Wada  = (const float*)d_in[13];
  const float* bada  = (const float*)d_in[14];
  const float* Wc1   = (const float*)d_in[15];
  const float* bc1   = (const float*)d_in[16];
  const float* Wc2   = (const float*)d_in[17];
  const float* bc2   = (const float*)d_in[18];
  const float* Wdbc1 = (const float*)d_in[19];
  const float* Wdt1  = (const float*)d_in[20];
  const float* bdt1  = (const float*)d_in[21];
  const float* Alog1 = (const float*)d_in[22];
  const float* Dp1   = (const float*)d_in[23];
  const float* Wdbc2 = (const float*)d_in[24];
  const float* Wdt2  = (const float*)d_in[25];
  const float* bdt2  = (const float*)d_in[26];
  const float* Alog2 = (const float*)d_in[27];
  const float* Dp2   = (const float*)d_in[28];

  const int M = B_ * S_;                 // 2048
  float* ws   = (float*)d_ws;
  float* ada  = ws;                      // 6144 used, pad to 8192
  float* skip = ada + 8192;              // 2,097,152
  float* xs2  = skip + 2097152;          // 2,097,152 (reused: dbc + Hbuf)
  float* mz   = xs2 + 2097152;           // 4,194,304 (reused as dlt later)
  float* amx  = mz + 4194304;            // 4,194,304
  float* z1   = amx + 4194304;           // 4,194,304
  float* z2   = z1 + 4194304;            // 4,194,304
  // aliases (dead buffers reused)
  float* dbc  = xs2;                     // 196,608 (xs2 dead after step 3)
  float* Hbuf = xs2 + 262144;            // 1,048,576 (fits in xs2's 2M slot)
  float* dlt  = mz;                      // 4,194,304 (mz dead after step 4)
  float* Pbuf = (float*)d_out;           // 1,048,576 scratch; fully overwritten by step 8

  // 1. adaLN params
  k_ada<<<dim3(B_ * 3 * D_), dim3(256), 0, stream>>>(c, Wada, bada, ada);
  // 2. LN1 + modulate + LN2
  k_ln<<<dim3(M), dim3(256), 0, stream>>>(x, n1g, n1b, n2g, n2b, ada, skip, xs2);
  // 3. mz = xs2 @ Wz^T + bz ; actmx = silu(xs2 @ Wx^T + bx)
  k_gemm<0><<<dim3(E_ / 64, M / 64), 256, 0, stream>>>(xs2, D_, Wz, bz, mz, M, E_, D_,
                                                       nullptr, nullptr, nullptr, nullptr);
  k_gemm<1><<<dim3(E_ / 64, M / 64), 256, 0, stream>>>(xs2, D_, Wx, bx, amx, M, E_, D_,
                                                       nullptr, nullptr, nullptr, nullptr);
  // 4. z1 = mz @ Wc1^T + bc1 ; z2 = mz @ Wc2^T + bc2
  k_gemm<0><<<dim3(E_ / 64, M / 64), 256, 0, stream>>>(mz, E_, Wc1, bc1, z1, M, E_, E_,
                                                       nullptr, nullptr, nullptr, nullptr);
  k_gemm<0><<<dim3(E_ / 64, M / 64), 256, 0, stream>>>(mz, E_, Wc2, bc2, z2, M, E_, E_,
                                                       nullptr, nullptr, nullptr, nullptr);
  // 5. branch 1: dbc, delta_pre, forward chunked scan (in-place on z1)
  k_gemm<0><<<dim3(2, M / 64), 256, 0, stream>>>(z1, E_, Wdbc1, nullptr, dbc, M, 96, E_,
                                                 nullptr, nullptr, nullptr, nullptr);
  k_gemm<0><<<dim3(E_ / 64, M / 64), 256, 0, stream>>>(dbc, 96, Wdt1, bdt1, dlt, M, E_, R_,
                                                       nullptr, nullptr, nullptr, nullptr);
  k_scan_chunk<false><<<dim3(256), dim3(256), 0, stream>>>(z1, dlt, dbc, Alog1, Pbuf, Hbuf);
  k_scan_comb<<<dim3(256), dim3(256), 0, stream>>>(Pbuf, Hbuf);
  k_scan_apply<false><<<dim3(256), dim3(256), 0, stream>>>(z1, dlt, dbc, Alog1, Dp1, Pbuf);
  // 6. branch 2: dbc, delta_pre, reverse chunked scan (in-place on z2; flips absorbed)
  k_gemm<0><<<dim3(2, M / 64), 256, 0, stream>>>(z2, E_, Wdbc2, nullptr, dbc, M, 96, E_,
                                                 nullptr, nullptr, nullptr, nullptr);
  k_gemm<0><<<dim3(E_ / 64, M / 64), 256, 0, stream>>>(dbc, 96, Wdt2, bdt2, dlt, M, E_, R_,
                                                       nullptr, nullptr, nullptr, nullptr);
  k_scan_chunk<true><<<dim3(256), dim3(256), 0, stream>>>(z2, dlt, dbc, Alog2, Pbuf, Hbuf);
  k_scan_comb<<<dim3(256), dim3(256), 0, stream>>>(Pbuf, Hbuf);
  k_scan_apply<true><<<dim3(256), dim3(256), 0, stream>>>(z2, dlt, dbc, Alog2, Dp2, Pbuf);
  // 7. ysum = actmx*(z1+z2) -> z1
  k_ysum<<<dim3((M * E_) / 256), 256, 0, stream>>>(z1, z2, amx);
  // 8. out = ysum @ Wf^T + bf + skip ; d_out = x + gate*out  (f32)
  k_gemm<2><<<dim3(D_ / 64, M / 64), 256, 0, stream>>>(z1, E_, Wf, bfb, nullptr, M, D_, E_,
                                                       skip, x, ada, (float*)d_out);
}

// Round 4
// 1002.414 us; speedup vs baseline: 4.0413x; 1.9413x over previous
//
#include <hip/hip_runtime.h>
#include <hip/hip_bf16.h>

#define EPSQ 1e-5f
// Problem sizes
#define B_ 2
#define S_ 1024
#define D_ 1024
#define E_ 2048
#define N_ 16
#define R_ 64
// Chunked scan config
#define CS_ 64
#define NC_ 16
#define CH_ 4096

typedef float f32x4 __attribute__((ext_vector_type(4)));
typedef short s16x8 __attribute__((ext_vector_type(8)));

static __device__ __forceinline__ unsigned short f2bf(float f) {
  unsigned int u = __float_as_uint(f);
  unsigned int r = (u + 0x7fff + ((u >> 16) & 1)) >> 16;   // round-to-nearest-even
  return (unsigned short)r;
}

static __device__ __forceinline__ s16x8 cvt8(float4 a, float4 b) {
  s16x8 r;
  r[0] = (short)f2bf(a.x); r[1] = (short)f2bf(a.y);
  r[2] = (short)f2bf(a.z); r[3] = (short)f2bf(a.w);
  r[4] = (short)f2bf(b.x); r[5] = (short)f2bf(b.y);
  r[6] = (short)f2bf(b.z); r[7] = (short)f2bf(b.w);
  return r;
}

static __device__ __forceinline__ float block_sum(float v, float* red) {
  int t = threadIdx.x;
  red[t] = v;
  __syncthreads();
  #pragma unroll
  for (int off = 128; off > 0; off >>= 1) {
    if (t < off) red[t] += red[t + off];
    __syncthreads();
  }
  float r = red[0];
  __syncthreads();
  return r;
}

// ada = silu(c) @ Wada^T + bada   -> [B, 3D] fp32
__global__ void k_ada(const float* __restrict__ c, const float* __restrict__ Wada,
                      const float* __restrict__ bada, float* __restrict__ ada) {
  __shared__ float red[256];
  int j = blockIdx.x % (3 * D_);
  int b = blockIdx.x / (3 * D_);
  const float* crow = c + (size_t)b * (2 * D_);
  const float* wrow = Wada + (size_t)j * (2 * D_);
  float acc = 0.f;
  for (int i = threadIdx.x; i < 2 * D_; i += 256) {
    float cv = crow[i];
    float s = cv / (1.f + __expf(-cv));      // silu
    acc += s * wrow[i];
  }
  float tot = block_sum(acc, red);
  if (threadIdx.x == 0) ada[(size_t)b * (3 * D_) + j] = tot + bada[j];
}

// LN1 -> modulate(scale,shift) -> skip ; LN2 -> xs2.  One block per (b,s) row.
__global__ void k_ln(const float* __restrict__ x,
                     const float* __restrict__ g1, const float* __restrict__ b1,
                     const float* __restrict__ g2, const float* __restrict__ b2,
                     const float* __restrict__ ada,
                     float* __restrict__ skip, float* __restrict__ xs2) {
  __shared__ float red[256];
  int row = blockIdx.x;            // b*S + s
  int b = row >> 10;               // S = 1024
  int t = threadIdx.x;
  const float* xr = x + (size_t)row * D_;

  float v[4];
  float4 xv = *(const float4*)(xr + t * 4);
  v[0] = xv.x; v[1] = xv.y; v[2] = xv.z; v[3] = xv.w;

  float s = v[0] + v[1] + v[2] + v[3];
  float mean = block_sum(s, red) * (1.f / D_);
  float q = 0.f;
  #pragma unroll
  for (int i = 0; i < 4; ++i) { float d = v[i] - mean; q += d * d; }
  float var = block_sum(q, red) * (1.f / D_);
  float rstd = rsqrtf(var + EPSQ);

  const float* shf = ada + (size_t)b * (3 * D_);
  const float* scl = shf + D_;
  float s2 = 0.f;
  #pragma unroll
  for (int i = 0; i < 4; ++i) {
    int d = t * 4 + i;
    float xn = (v[i] - mean) * rstd * g1[d] + b1[d];
    float tt = xn * (1.f + scl[d]) + shf[d];
    v[i] = tt;
    s2 += tt;
    skip[(size_t)row * D_ + d] = tt;
  }
  float mean2 = block_sum(s2, red) * (1.f / D_);
  float q2 = 0.f;
  #pragma unroll
  for (int i = 0; i < 4; ++i) { float d = v[i] - mean2; q2 += d * d; }
  float var2 = block_sum(q2, red) * (1.f / D_);
  float rstd2 = rsqrtf(var2 + EPSQ);
  #pragma unroll
  for (int i = 0; i < 4; ++i) {
    int d = t * 4 + i;
    xs2[(size_t)row * D_ + d] = (v[i] - mean2) * rstd2 * g2[d] + b2[d];
  }
}

// ---------------- MFMA GEMM (bf16 inputs via on-the-fly cvt, f32 accum) -------------
// C[M,Nn] = A[M,K] @ W[Nn,K]^T + bias.  Tile 128x128, BK=32, 4 waves (2x2).
// Requires: M%128==0, Nn%128==0, K%32==0.
// EPI 0: store f32 ; EPI 1: silu ; EPI 2: final out o = x + gate*(v+skip)
template <int EPI>
__global__ __launch_bounds__(256) void k_mgemm(
    const float* __restrict__ A, int lda,
    const float* __restrict__ W, const float* __restrict__ bias,
    float* __restrict__ C, int Nn, int K,
    const float* __restrict__ skip, const float* __restrict__ xin,
    const float* __restrict__ ada, float* __restrict__ obf) {
  __shared__ __align__(16) unsigned short lA[4096];   // 128 rows x 32 k, swizzled
  __shared__ __align__(16) unsigned short lB[4096];
  const int t = threadIdx.x;
  const int lane = t & 63, wid = t >> 6;
  const int wr = wid >> 1, wc = wid & 1;
  const int m0 = blockIdx.y * 128, n0 = blockIdx.x * 128;

  f32x4 acc[4][4];
  #pragma unroll
  for (int m = 0; m < 4; ++m)
    #pragma unroll
    for (int n = 0; n < 4; ++n) acc[m][n] = (f32x4){0.f, 0.f, 0.f, 0.f};

  // fragment read offsets (bytes, swizzled)
  const int frow = lane & 15, fkg = lane >> 4;
  int aoff[4], boff[4];
  #pragma unroll
  for (int m = 0; m < 4; ++m) {
    int row = wr * 64 + m * 16 + frow;
    aoff[m] = (row * 64 + fkg * 16) ^ ((row & 7) << 4);
  }
  #pragma unroll
  for (int n = 0; n < 4; ++n) {
    int col = wc * 64 + n * 16 + frow;
    boff[n] = (col * 64 + fkg * 16) ^ ((col & 7) << 4);
  }

  // staging: slot s = t (row s>>2 in 0..63, kg = s&3) and +64 rows
  const int sr = t >> 2, sk = (t & 3) * 8;
  const int w0 = (sr * 64 + (t & 3) * 16) ^ ((sr & 7) << 4);
  const int w1 = w0 + 4096;   // +64 rows
  const float* pa0 = A + (size_t)(m0 + sr) * lda + sk;
  const float* pa1 = A + (size_t)(m0 + sr + 64) * lda + sk;
  const float* pb0 = W + (size_t)(n0 + sr) * K + sk;
  const float* pb1 = W + (size_t)(n0 + sr + 64) * K + sk;

  for (int k0 = 0; k0 < K; k0 += 32) {
    float4 a00 = *(const float4*)(pa0 + k0);
    float4 a01 = *(const float4*)(pa0 + k0 + 4);
    float4 a10 = *(const float4*)(pa1 + k0);
    float4 a11 = *(const float4*)(pa1 + k0 + 4);
    float4 b00 = *(const float4*)(pb0 + k0);
    float4 b01 = *(const float4*)(pb0 + k0 + 4);
    float4 b10 = *(const float4*)(pb1 + k0);
    float4 b11 = *(const float4*)(pb1 + k0 + 4);
    __syncthreads();   // previous iteration's reads complete
    *(s16x8*)((char*)lA + w0) = cvt8(a00, a01);
    *(s16x8*)((char*)lA + w1) = cvt8(a10, a11);
    *(s16x8*)((char*)lB + w0) = cvt8(b00, b01);
    *(s16x8*)((char*)lB + w1) = cvt8(b10, b11);
    __syncthreads();
    s16x8 af[4], bfr[4];
    #pragma unroll
    for (int m = 0; m < 4; ++m) af[m] = *(const s16x8*)((const char*)lA + aoff[m]);
    #pragma unroll
    for (int n = 0; n < 4; ++n) bfr[n] = *(const s16x8*)((const char*)lB + boff[n]);
    #pragma unroll
    for (int m = 0; m < 4; ++m)
      #pragma unroll
      for (int n = 0; n < 4; ++n)
        acc[m][n] = __builtin_amdgcn_mfma_f32_16x16x32_bf16(af[m], bfr[n], acc[m][n], 0, 0, 0);
  }

  // epilogue: D layout col = lane&15, row = (lane>>4)*4 + j
  #pragma unroll
  for (int m = 0; m < 4; ++m) {
    int rbase = m0 + wr * 64 + m * 16 + fkg * 4;
    #pragma unroll
    for (int n = 0; n < 4; ++n) {
      int col = n0 + wc * 64 + n * 16 + frow;
      float bv = bias ? bias[col] : 0.f;
      #pragma unroll
      for (int j = 0; j < 4; ++j) {
        int row = rbase + j;
        float v = acc[m][n][j] + bv;
        if constexpr (EPI == 1) { v = v / (1.f + __expf(-v)); }
        if constexpr (EPI == 2) {
          int b = row >> 10;
          float gate = ada[(size_t)b * (3 * D_) + 2 * D_ + col];
          float o = v + skip[(size_t)row * D_ + col];
          obf[(size_t)row * D_ + col] = xin[(size_t)row * D_ + col] + gate * o;
        } else {
          C[(size_t)row * Nn + col] = v;
        }
      }
    }
  }
}

// ---------------- naive fp32 GEMM (small shapes: dbc N=96, dlt K=64) ----------------
__global__ void k_gemm(const float* __restrict__ A, int lda,
                       const float* __restrict__ W, const float* __restrict__ bias,
                       float* __restrict__ C, int M, int Nn, int K) {
  const int BK = 16;
  __shared__ float As[BK][65];
  __shared__ float Bs[BK][65];
  int n0 = blockIdx.x * 64, m0 = blockIdx.y * 64;
  int t = threadIdx.x;
  int tx = t & 15, ty = t >> 4;
  int ar = t >> 2, ac4 = (t & 3) * 4;
  float acc[4][4] = {};

  for (int k0 = 0; k0 < K; k0 += BK) {
    const float* ap = A + (size_t)(m0 + ar) * lda + k0 + ac4;
    float4 av = *(const float4*)ap;
    As[ac4 + 0][ar] = av.x; As[ac4 + 1][ar] = av.y;
    As[ac4 + 2][ar] = av.z; As[ac4 + 3][ar] = av.w;

    int wn = n0 + ar;
    if (wn < Nn) {
      const float* wp = W + (size_t)wn * K + k0 + ac4;
      float4 wv = *(const float4*)wp;
      Bs[ac4 + 0][ar] = wv.x; Bs[ac4 + 1][ar] = wv.y;
      Bs[ac4 + 2][ar] = wv.z; Bs[ac4 + 3][ar] = wv.w;
    } else {
      Bs[ac4 + 0][ar] = 0.f; Bs[ac4 + 1][ar] = 0.f;
      Bs[ac4 + 2][ar] = 0.f; Bs[ac4 + 3][ar] = 0.f;
    }
    __syncthreads();
    #pragma unroll
    for (int kk = 0; kk < BK; ++kk) {
      float a0 = As[kk][ty * 4 + 0], a1 = As[kk][ty * 4 + 1];
      float a2 = As[kk][ty * 4 + 2], a3 = As[kk][ty * 4 + 3];
      float c0 = Bs[kk][tx * 4 + 0], c1 = Bs[kk][tx * 4 + 1];
      float c2 = Bs[kk][tx * 4 + 2], c3 = Bs[kk][tx * 4 + 3];
      acc[0][0] += a0 * c0; acc[0][1] += a0 * c1; acc[0][2] += a0 * c2; acc[0][3] += a0 * c3;
      acc[1][0] += a1 * c0; acc[1][1] += a1 * c1; acc[1][2] += a1 * c2; acc[1][3] += a1 * c3;
      acc[2][0] += a2 * c0; acc[2][1] += a2 * c1; acc[2][2] += a2 * c2; acc[2][3] += a2 * c3;
      acc[3][0] += a3 * c0; acc[3][1] += a3 * c1; acc[3][2] += a3 * c2; acc[3][3] += a3 * c3;
    }
    __syncthreads();
  }

  #pragma unroll
  for (int i = 0; i < 4; ++i) {
    int row = m0 + ty * 4 + i;
    #pragma unroll
    for (int j = 0; j < 4; ++j) {
      int col = n0 + tx * 4 + j;
      if (col >= Nn) continue;
      float v = acc[i][j];
      if (bias) v += bias[col];
      C[(size_t)row * Nn + col] = v;
    }
  }
}

static __device__ __forceinline__ float softplusf(float dv) {
  return (dv > 20.f) ? dv : log1pf(__expf(dv));
}

// ---- Chunked parallel scan (3 passes) ----
template <bool REV>
__global__ void k_scan_chunk(const float* __restrict__ u, const float* __restrict__ dlt,
                             const float* __restrict__ dbc, const float* __restrict__ Alog,
                             float* __restrict__ Pbuf, float* __restrict__ Hbuf) {
  int ch = (blockIdx.x & 15) * 256 + threadIdx.x;
  int c  = blockIdx.x >> 4;
  int b = ch >> 11, e = ch & (E_ - 1);
  float A[N_], P[N_], h[N_];
  #pragma unroll
  for (int n = 0; n < N_; ++n) {
    A[n] = -__expf(Alog[(size_t)e * N_ + n]);
    P[n] = 1.f; h[n] = 0.f;
  }
  for (int t = 0; t < CS_; ++t) {
    int tau = c * CS_ + t;
    int s = REV ? (S_ - 1 - tau) : tau;
    size_t row = (size_t)b * S_ + s;
    float uu = u[row * E_ + e];
    float dv = dlt[row * E_ + e];
    float delta = softplusf(dv);
    float du = delta * uu;
    const float* bc = dbc + row * 96;
    #pragma unroll
    for (int n = 0; n < N_; ++n) {
      float dA = __expf(delta * A[n]);
      P[n] *= dA;
      h[n] = dA * h[n] + du * bc[64 + n];
    }
  }
  #pragma unroll
  for (int n = 0; n < N_; ++n) {
    size_t off = (size_t)(c * N_ + n) * CH_ + ch;
    Pbuf[off] = P[n];
    Hbuf[off] = h[n];
  }
}

__global__ void k_scan_comb(float* __restrict__ Pbuf, const float* __restrict__ Hbuf) {
  int idx = blockIdx.x * 256 + threadIdx.x;
  int ch = idx & (CH_ - 1);
  int n  = idx >> 12;
  float hcur = 0.f;
  for (int c = 0; c < NC_; ++c) {
    size_t off = (size_t)(c * N_ + n) * CH_ + ch;
    float p  = Pbuf[off];
    float hl = Hbuf[off];
    Pbuf[off] = hcur;
    hcur = p * hcur + hl;
  }
}

template <bool REV>
__global__ void k_scan_apply(float* __restrict__ u, const float* __restrict__ dlt,
                             const float* __restrict__ dbc, const float* __restrict__ Alog,
                             const float* __restrict__ Dp, const float* __restrict__ Pbuf) {
  int ch = (blockIdx.x & 15) * 256 + threadIdx.x;
  int c  = blockIdx.x >> 4;
  int b = ch >> 11, e = ch & (E_ - 1);
  float A[N_], h[N_];
  #pragma unroll
  for (int n = 0; n < N_; ++n) {
    A[n] = -__expf(Alog[(size_t)e * N_ + n]);
    h[n] = Pbuf[(size_t)(c * N_ + n) * CH_ + ch];
  }
  float dp = Dp[e];
  for (int t = 0; t < CS_; ++t) {
    int tau = c * CS_ + t;
    int s = REV ? (S_ - 1 - tau) : tau;
    size_t row = (size_t)b * S_ + s;
    float uu = u[row * E_ + e];
    float dv = dlt[row * E_ + e];
    float delta = softplusf(dv);
    float du = delta * uu;
    const float* bc = dbc + row * 96;
    float y = 0.f;
    #pragma unroll
    for (int n = 0; n < N_; ++n) {
      float dA = __expf(delta * A[n]);
      h[n] = dA * h[n] + du * bc[64 + n];
      y += h[n] * bc[80 + n];
    }
    u[row * E_ + e] = y + uu * dp;
  }
}

// z1 <- actmx * (z1 + z2)
__global__ void k_ysum(float* __restrict__ z1, const float* __restrict__ z2,
                       const float* __restrict__ amx) {
  size_t i = (size_t)blockIdx.x * 256 + threadIdx.x;
  z1[i] = amx[i] * (z1[i] + z2[i]);
}

extern "C" void kernel_launch(void* const* d_in, const int* in_sizes, int n_in,
                              void* d_out, int out_size, void* d_ws, size_t ws_size,
                              hipStream_t stream) {
  const float* x     = (const float*)d_in[0];
  const float* c     = (const float*)d_in[1];
  const float* n1g   = (const float*)d_in[3];
  const float* n1b   = (const float*)d_in[4];
  const float* n2g   = (const float*)d_in[5];
  const float* n2b   = (const float*)d_in[6];
  const float* Wx    = (const float*)d_in[7];
  const float* bx    = (const float*)d_in[8];
  const float* Wz    = (const float*)d_in[9];
  const float* bz    = (const float*)d_in[10];
  const float* Wf    = (const float*)d_in[11];
  const float* bfb   = (const float*)d_in[12];
  const float* Wada  = (const float*)d_in[13];
  const float* bada  = (const float*)d_in[14];
  const float* Wc1   = (const float*)d_in[15];
  const float* bc1   = (const float*)d_in[16];
  const float* Wc2   = (const float*)d_in[17];
  const float* bc2   = (const float*)d_in[18];
  const float* Wdbc1 = (const float*)d_in[19];
  const float* Wdt1  = (const float*)d_in[20];
  const float* bdt1  = (const float*)d_in[21];
  const float* Alog1 = (const float*)d_in[22];
  const float* Dp1   = (const float*)d_in[23];
  const float* Wdbc2 = (const float*)d_in[24];
  const float* Wdt2  = (const float*)d_in[25];
  const float* bdt2  = (const float*)d_in[26];
  const float* Alog2 = (const float*)d_in[27];
  const float* Dp2   = (const float*)d_in[28];

  const int M = B_ * S_;                 // 2048
  float* ws   = (float*)d_ws;
  float* ada  = ws;                      // 8192
  float* skip = ada + 8192;              // 2,097,152
  float* xs2  = skip + 2097152;          // 2,097,152 (reused: dbc + Hbuf)
  float* mz   = xs2 + 2097152;           // 4,194,304 (reused as dlt later)
  float* amx  = mz + 4194304;            // 4,194,304
  float* z1   = amx + 4194304;           // 4,194,304
  float* z2   = z1 + 4194304;            // 4,194,304
  float* dbc  = xs2;                     // alias (xs2 dead after step 3)
  float* Hbuf = xs2 + 262144;            // alias
  float* dlt  = mz;                      // alias (mz dead after step 4)
  float* Pbuf = (float*)d_out;           // scratch; fully overwritten by step 8

  // 1. adaLN params
  k_ada<<<dim3(B_ * 3 * D_), dim3(256), 0, stream>>>(c, Wada, bada, ada);
  // 2. LN1 + modulate + LN2
  k_ln<<<dim3(M), dim3(256), 0, stream>>>(x, n1g, n1b, n2g, n2b, ada, skip, xs2);
  // 3. mz = xs2 @ Wz^T + bz ; actmx = silu(xs2 @ Wx^T + bx)   [MFMA]
  k_mgemm<0><<<dim3(E_ / 128, M / 128), 256, 0, stream>>>(xs2, D_, Wz, bz, mz, E_, D_,
                                                          nullptr, nullptr, nullptr, nullptr);
  k_mgemm<1><<<dim3(E_ / 128, M / 128), 256, 0, stream>>>(xs2, D_, Wx, bx, amx, E_, D_,
                                                          nullptr, nullptr, nullptr, nullptr);
  // 4. z1 = mz @ Wc1^T + bc1 ; z2 = mz @ Wc2^T + bc2   [MFMA]
  k_mgemm<0><<<dim3(E_ / 128, M / 128), 256, 0, stream>>>(mz, E_, Wc1, bc1, z1, E_, E_,
                                                          nullptr, nullptr, nullptr, nullptr);
  k_mgemm<0><<<dim3(E_ / 128, M / 128), 256, 0, stream>>>(mz, E_, Wc2, bc2, z2, E_, E_,
                                                          nullptr, nullptr, nullptr, nullptr);
  // 5. branch 1: dbc, delta_pre, forward chunked scan (in-place on z1)
  k_gemm<<<dim3(2, M / 64), 256, 0, stream>>>(z1, E_, Wdbc1, nullptr, dbc, M, 96, E_);
  k_gemm<<<dim3(E_ / 64, M / 64), 256, 0, stream>>>(dbc, 96, Wdt1, bdt1, dlt, M, E_, R_);
  k_scan_chunk<false><<<dim3(256), dim3(256), 0, stream>>>(z1, dlt, dbc, Alog1, Pbuf, Hbuf);
  k_scan_comb<<<dim3(256), dim3(256), 0, stream>>>(Pbuf, Hbuf);
  k_scan_apply<false><<<dim3(256), dim3(256), 0, stream>>>(z1, dlt, dbc, Alog1, Dp1, Pbuf);
  // 6. branch 2: dbc, delta_pre, reverse chunked scan (in-place on z2)
  k_gemm<<<dim3(2, M / 64), 256, 0, stream>>>(z2, E_, Wdbc2, nullptr, dbc, M, 96, E_);
  k_gemm<<<dim3(E_ / 64, M / 64), 256, 0, stream>>>(dbc, 96, Wdt2, bdt2, dlt, M, E_, R_);
  k_scan_chunk<true><<<dim3(256), dim3(256), 0, stream>>>(z2, dlt, dbc, Alog2, Pbuf, Hbuf);
  k_scan_comb<<<dim3(256), dim3(256), 0, stream>>>(Pbuf, Hbuf);
  k_scan_apply<true><<<dim3(256), dim3(256), 0, stream>>>(z2, dlt, dbc, Alog2, Dp2, Pbuf);
  // 7. ysum = actmx*(z1+z2) -> z1
  k_ysum<<<dim3((M * E_) / 256), 256, 0, stream>>>(z1, z2, amx);
  // 8. out = ysum @ Wf^T + bf + skip ; d_out = x + gate*out   [MFMA]
  k_mgemm<2><<<dim3(D_ / 128, M / 128), 256, 0, stream>>>(z1, E_, Wf, bfb, nullptr, D_, E_,
                                                          skip, x, ada, (float*)d_out);
}

// Round 5
// 619.299 us; speedup vs baseline: 6.5414x; 1.6186x over previous
//
#include <hip/hip_runtime.h>
#include <hip/hip_bf16.h>

#define EPSQ 1e-5f
// Problem sizes
#define B_ 2
#define S_ 1024
#define D_ 1024
#define E_ 2048
#define N_ 16
#define R_ 64
// Chunked scan config
#define CS_ 64
#define NC_ 16
#define CH_ 4096
// dbc split-K config
#define KSPLIT_ 8
#define KCH_ 256   // E_/KSPLIT_

typedef float f32x4 __attribute__((ext_vector_type(4)));
typedef short s16x8 __attribute__((ext_vector_type(8)));

static __device__ __forceinline__ short f2bf_s(float f) {
  __hip_bfloat16 h = __float2bfloat16(f);
  return *reinterpret_cast<short*>(&h);
}

static __device__ __forceinline__ s16x8 cvt8(float4 a, float4 b) {
  s16x8 r;
  r[0] = f2bf_s(a.x); r[1] = f2bf_s(a.y); r[2] = f2bf_s(a.z); r[3] = f2bf_s(a.w);
  r[4] = f2bf_s(b.x); r[5] = f2bf_s(b.y); r[6] = f2bf_s(b.z); r[7] = f2bf_s(b.w);
  return r;
}

static __device__ __forceinline__ float block_sum(float v, float* red) {
  int t = threadIdx.x;
  red[t] = v;
  __syncthreads();
  #pragma unroll
  for (int off = 128; off > 0; off >>= 1) {
    if (t < off) red[t] += red[t + off];
    __syncthreads();
  }
  float r = red[0];
  __syncthreads();
  return r;
}

// ada = silu(c) @ Wada^T + bada   -> [B, 3D] fp32
__global__ void k_ada(const float* __restrict__ c, const float* __restrict__ Wada,
                      const float* __restrict__ bada, float* __restrict__ ada) {
  __shared__ float red[256];
  int j = blockIdx.x % (3 * D_);
  int b = blockIdx.x / (3 * D_);
  const float* crow = c + (size_t)b * (2 * D_);
  const float* wrow = Wada + (size_t)j * (2 * D_);
  float acc = 0.f;
  for (int i = threadIdx.x; i < 2 * D_; i += 256) {
    float cv = crow[i];
    float s = cv / (1.f + __expf(-cv));      // silu
    acc += s * wrow[i];
  }
  float tot = block_sum(acc, red);
  if (threadIdx.x == 0) ada[(size_t)b * (3 * D_) + j] = tot + bada[j];
}

// LN1 -> modulate(scale,shift) -> skip ; LN2 -> xs2.  One block per (b,s) row.
__global__ void k_ln(const float* __restrict__ x,
                     const float* __restrict__ g1, const float* __restrict__ b1,
                     const float* __restrict__ g2, const float* __restrict__ b2,
                     const float* __restrict__ ada,
                     float* __restrict__ skip, float* __restrict__ xs2) {
  __shared__ float red[256];
  int row = blockIdx.x;            // b*S + s
  int b = row >> 10;               // S = 1024
  int t = threadIdx.x;
  const float* xr = x + (size_t)row * D_;

  float v[4];
  float4 xv = *(const float4*)(xr + t * 4);
  v[0] = xv.x; v[1] = xv.y; v[2] = xv.z; v[3] = xv.w;

  float s = v[0] + v[1] + v[2] + v[3];
  float mean = block_sum(s, red) * (1.f / D_);
  float q = 0.f;
  #pragma unroll
  for (int i = 0; i < 4; ++i) { float d = v[i] - mean; q += d * d; }
  float var = block_sum(q, red) * (1.f / D_);
  float rstd = rsqrtf(var + EPSQ);

  const float* shf = ada + (size_t)b * (3 * D_);
  const float* scl = shf + D_;
  float s2 = 0.f;
  #pragma unroll
  for (int i = 0; i < 4; ++i) {
    int d = t * 4 + i;
    float xn = (v[i] - mean) * rstd * g1[d] + b1[d];
    float tt = xn * (1.f + scl[d]) + shf[d];
    v[i] = tt;
    s2 += tt;
    skip[(size_t)row * D_ + d] = tt;
  }
  float mean2 = block_sum(s2, red) * (1.f / D_);
  float q2 = 0.f;
  #pragma unroll
  for (int i = 0; i < 4; ++i) { float d = v[i] - mean2; q2 += d * d; }
  float var2 = block_sum(q2, red) * (1.f / D_);
  float rstd2 = rsqrtf(var2 + EPSQ);
  #pragma unroll
  for (int i = 0; i < 4; ++i) {
    int d = t * 4 + i;
    xs2[(size_t)row * D_ + d] = (v[i] - mean2) * rstd2 * g2[d] + b2[d];
  }
}

// ---------------- MFMA GEMM (bf16 via on-the-fly cvt, f32 accum) -------------
// C[M,Nn] = A[M,K] @ W[Nn,K]^T + bias.  Tile 128x128, BK=32, 4 waves (2x2).
// Depth-1 global prefetch: next k-step's loads issue under current MFMAs.
template <int EPI>
__global__ __launch_bounds__(256) void k_mgemm(
    const float* __restrict__ A, int lda,
    const float* __restrict__ W, const float* __restrict__ bias,
    float* __restrict__ C, int Nn, int K,
    const float* __restrict__ skip, const float* __restrict__ xin,
    const float* __restrict__ ada, float* __restrict__ obf) {
  __shared__ __align__(16) unsigned short lA[4096];   // 128 rows x 32 k, swizzled
  __shared__ __align__(16) unsigned short lB[4096];
  const int t = threadIdx.x;
  const int lane = t & 63, wid = t >> 6;
  const int wr = wid >> 1, wc = wid & 1;
  const int m0 = blockIdx.y * 128, n0 = blockIdx.x * 128;

  f32x4 acc[4][4];
  #pragma unroll
  for (int m = 0; m < 4; ++m)
    #pragma unroll
    for (int n = 0; n < 4; ++n) acc[m][n] = (f32x4){0.f, 0.f, 0.f, 0.f};

  // fragment read offsets (bytes, swizzled)
  const int frow = lane & 15, fkg = lane >> 4;
  int aoff[4], boff[4];
  #pragma unroll
  for (int m = 0; m < 4; ++m) {
    int row = wr * 64 + m * 16 + frow;
    aoff[m] = (row * 64 + fkg * 16) ^ ((row & 7) << 4);
  }
  #pragma unroll
  for (int n = 0; n < 4; ++n) {
    int col = wc * 64 + n * 16 + frow;
    boff[n] = (col * 64 + fkg * 16) ^ ((col & 7) << 4);
  }

  const int sr = t >> 2, sk = (t & 3) * 8;
  const int w0 = (sr * 64 + (t & 3) * 16) ^ ((sr & 7) << 4);
  const int w1 = w0 + 4096;   // +64 rows
  const float* pa0 = A + (size_t)(m0 + sr) * lda + sk;
  const float* pa1 = A + (size_t)(m0 + sr + 64) * lda + sk;
  const float* pb0 = W + (size_t)(n0 + sr) * K + sk;
  const float* pb1 = W + (size_t)(n0 + sr + 64) * K + sk;

  float4 a00 = *(const float4*)(pa0);
  float4 a01 = *(const float4*)(pa0 + 4);
  float4 a10 = *(const float4*)(pa1);
  float4 a11 = *(const float4*)(pa1 + 4);
  float4 b00 = *(const float4*)(pb0);
  float4 b01 = *(const float4*)(pb0 + 4);
  float4 b10 = *(const float4*)(pb1);
  float4 b11 = *(const float4*)(pb1 + 4);

  for (int k0 = 0; k0 < K; k0 += 32) {
    __syncthreads();   // previous iteration's ds_reads complete
    *(s16x8*)((char*)lA + w0) = cvt8(a00, a01);
    *(s16x8*)((char*)lA + w1) = cvt8(a10, a11);
    *(s16x8*)((char*)lB + w0) = cvt8(b00, b01);
    *(s16x8*)((char*)lB + w1) = cvt8(b10, b11);
    __syncthreads();
    int kn = k0 + 32;
    if (kn < K) {      // issue next-step loads early; latency hides under MFMA
      a00 = *(const float4*)(pa0 + kn); a01 = *(const float4*)(pa0 + kn + 4);
      a10 = *(const float4*)(pa1 + kn); a11 = *(const float4*)(pa1 + kn + 4);
      b00 = *(const float4*)(pb0 + kn); b01 = *(const float4*)(pb0 + kn + 4);
      b10 = *(const float4*)(pb1 + kn); b11 = *(const float4*)(pb1 + kn + 4);
    }
    s16x8 af[4], bfr[4];
    #pragma unroll
    for (int m = 0; m < 4; ++m) af[m] = *(const s16x8*)((const char*)lA + aoff[m]);
    #pragma unroll
    for (int n = 0; n < 4; ++n) bfr[n] = *(const s16x8*)((const char*)lB + boff[n]);
    #pragma unroll
    for (int m = 0; m < 4; ++m)
      #pragma unroll
      for (int n = 0; n < 4; ++n)
        acc[m][n] = __builtin_amdgcn_mfma_f32_16x16x32_bf16(af[m], bfr[n], acc[m][n], 0, 0, 0);
  }

  // epilogue: D layout col = lane&15, row = (lane>>4)*4 + j
  #pragma unroll
  for (int m = 0; m < 4; ++m) {
    int rbase = m0 + wr * 64 + m * 16 + fkg * 4;
    #pragma unroll
    for (int n = 0; n < 4; ++n) {
      int col = n0 + wc * 64 + n * 16 + frow;
      float bv = bias ? bias[col] : 0.f;
      #pragma unroll
      for (int j = 0; j < 4; ++j) {
        int row = rbase + j;
        float v = acc[m][n][j] + bv;
        if constexpr (EPI == 1) { v = v / (1.f + __expf(-v)); }
        if constexpr (EPI == 2) {
          int b = row >> 10;
          float gate = ada[(size_t)b * (3 * D_) + 2 * D_ + col];
          float o = v + skip[(size_t)row * D_ + col];
          obf[(size_t)row * D_ + col] = xin[(size_t)row * D_ + col] + gate * o;
        } else {
          C[(size_t)row * Nn + col] = v;
        }
      }
    }
  }
}

// ---------------- naive fp32 GEMM (dlt: N=2048, K=64) -------------------------
// SP=true: apply softplus to the result (delta = softplus(. + bias))
template <bool SP>
__global__ void k_gemm(const float* __restrict__ A, int lda,
                       const float* __restrict__ W, const float* __restrict__ bias,
                       float* __restrict__ C, int M, int Nn, int K) {
  const int BK = 16;
  __shared__ float As[BK][65];
  __shared__ float Bs[BK][65];
  int n0 = blockIdx.x * 64, m0 = blockIdx.y * 64;
  int t = threadIdx.x;
  int tx = t & 15, ty = t >> 4;
  int ar = t >> 2, ac4 = (t & 3) * 4;
  float acc[4][4] = {};

  for (int k0 = 0; k0 < K; k0 += BK) {
    const float* ap = A + (size_t)(m0 + ar) * lda + k0 + ac4;
    float4 av = *(const float4*)ap;
    As[ac4 + 0][ar] = av.x; As[ac4 + 1][ar] = av.y;
    As[ac4 + 2][ar] = av.z; As[ac4 + 3][ar] = av.w;

    int wn = n0 + ar;
    if (wn < Nn) {
      const float* wp = W + (size_t)wn * K + k0 + ac4;
      float4 wv = *(const float4*)wp;
      Bs[ac4 + 0][ar] = wv.x; Bs[ac4 + 1][ar] = wv.y;
      Bs[ac4 + 2][ar] = wv.z; Bs[ac4 + 3][ar] = wv.w;
    } else {
      Bs[ac4 + 0][ar] = 0.f; Bs[ac4 + 1][ar] = 0.f;
      Bs[ac4 + 2][ar] = 0.f; Bs[ac4 + 3][ar] = 0.f;
    }
    __syncthreads();
    #pragma unroll
    for (int kk = 0; kk < BK; ++kk) {
      float a0 = As[kk][ty * 4 + 0], a1 = As[kk][ty * 4 + 1];
      float a2 = As[kk][ty * 4 + 2], a3 = As[kk][ty * 4 + 3];
      float c0 = Bs[kk][tx * 4 + 0], c1 = Bs[kk][tx * 4 + 1];
      float c2 = Bs[kk][tx * 4 + 2], c3 = Bs[kk][tx * 4 + 3];
      acc[0][0] += a0 * c0; acc[0][1] += a0 * c1; acc[0][2] += a0 * c2; acc[0][3] += a0 * c3;
      acc[1][0] += a1 * c0; acc[1][1] += a1 * c1; acc[1][2] += a1 * c2; acc[1][3] += a1 * c3;
      acc[2][0] += a2 * c0; acc[2][1] += a2 * c1; acc[2][2] += a2 * c2; acc[2][3] += a2 * c3;
      acc[3][0] += a3 * c0; acc[3][1] += a3 * c1; acc[3][2] += a3 * c2; acc[3][3] += a3 * c3;
    }
    __syncthreads();
  }

  #pragma unroll
  for (int i = 0; i < 4; ++i) {
    int row = m0 + ty * 4 + i;
    #pragma unroll
    for (int j = 0; j < 4; ++j) {
      int col = n0 + tx * 4 + j;
      if (col >= Nn) continue;
      float v = acc[i][j];
      if (bias) v += bias[col];
      if constexpr (SP) { v = (v > 20.f) ? v : log1pf(__expf(v)); }
      C[(size_t)row * Nn + col] = v;
    }
  }
}

// ---------------- dbc split-K: Part[kz] = z[:, kz*256:+256] @ Wdbc[:, same]^T ----
__global__ void k_dbc_split(const float* __restrict__ A, const float* __restrict__ W,
                            float* __restrict__ Part) {
  const int BK = 16;
  __shared__ float As[BK][65];
  __shared__ float Bs[BK][65];
  int n0 = blockIdx.x * 64, m0 = blockIdx.y * 64;
  int kbase = blockIdx.z * KCH_;
  int t = threadIdx.x;
  int tx = t & 15, ty = t >> 4;
  int ar = t >> 2, ac4 = (t & 3) * 4;
  float acc[4][4] = {};

  for (int k0 = 0; k0 < KCH_; k0 += BK) {
    const float* ap = A + (size_t)(m0 + ar) * E_ + kbase + k0 + ac4;
    float4 av = *(const float4*)ap;
    As[ac4 + 0][ar] = av.x; As[ac4 + 1][ar] = av.y;
    As[ac4 + 2][ar] = av.z; As[ac4 + 3][ar] = av.w;

    int wn = n0 + ar;
    if (wn < 96) {
      const float* wp = W + (size_t)wn * E_ + kbase + k0 + ac4;
      float4 wv = *(const float4*)wp;
      Bs[ac4 + 0][ar] = wv.x; Bs[ac4 + 1][ar] = wv.y;
      Bs[ac4 + 2][ar] = wv.z; Bs[ac4 + 3][ar] = wv.w;
    } else {
      Bs[ac4 + 0][ar] = 0.f; Bs[ac4 + 1][ar] = 0.f;
      Bs[ac4 + 2][ar] = 0.f; Bs[ac4 + 3][ar] = 0.f;
    }
    __syncthreads();
    #pragma unroll
    for (int kk = 0; kk < BK; ++kk) {
      float a0 = As[kk][ty * 4 + 0], a1 = As[kk][ty * 4 + 1];
      float a2 = As[kk][ty * 4 + 2], a3 = As[kk][ty * 4 + 3];
      float c0 = Bs[kk][tx * 4 + 0], c1 = Bs[kk][tx * 4 + 1];
      float c2 = Bs[kk][tx * 4 + 2], c3 = Bs[kk][tx * 4 + 3];
      acc[0][0] += a0 * c0; acc[0][1] += a0 * c1; acc[0][2] += a0 * c2; acc[0][3] += a0 * c3;
      acc[1][0] += a1 * c0; acc[1][1] += a1 * c1; acc[1][2] += a1 * c2; acc[1][3] += a1 * c3;
      acc[2][0] += a2 * c0; acc[2][1] += a2 * c1; acc[2][2] += a2 * c2; acc[2][3] += a2 * c3;
      acc[3][0] += a3 * c0; acc[3][1] += a3 * c1; acc[3][2] += a3 * c2; acc[3][3] += a3 * c3;
    }
    __syncthreads();
  }

  #pragma unroll
  for (int i = 0; i < 4; ++i) {
    int row = m0 + ty * 4 + i;
    #pragma unroll
    for (int j = 0; j < 4; ++j) {
      int col = n0 + tx * 4 + j;
      if (col < 96)
        Part[(size_t)blockIdx.z * (B_ * S_ * 96) + (size_t)row * 96 + col] = acc[i][j];
    }
  }
}

__global__ void k_dbc_reduce(const float* __restrict__ Part, float* __restrict__ dbc) {
  int i = blockIdx.x * 256 + threadIdx.x;   // < M*96
  float s = 0.f;
  #pragma unroll
  for (int kz = 0; kz < KSPLIT_; ++kz) s += Part[(size_t)kz * (B_ * S_ * 96) + i];
  dbc[i] = s;
}

// ---- Chunked parallel scan (3 passes). dlt now holds delta (softplus applied). ----
template <bool REV>
__global__ void k_scan_chunk(const float* __restrict__ u, const float* __restrict__ dlt,
                             const float* __restrict__ dbc, const float* __restrict__ Alog,
                             float* __restrict__ Pbuf, float* __restrict__ Hbuf) {
  int ch = (blockIdx.x & 15) * 256 + threadIdx.x;
  int c  = blockIdx.x >> 4;
  int b = ch >> 11, e = ch & (E_ - 1);
  float A[N_], P[N_], h[N_];
  #pragma unroll
  for (int n = 0; n < N_; ++n) {
    A[n] = -__expf(Alog[(size_t)e * N_ + n]);
    P[n] = 1.f; h[n] = 0.f;
  }
  for (int t = 0; t < CS_; ++t) {
    int tau = c * CS_ + t;
    int s = REV ? (S_ - 1 - tau) : tau;
    size_t row = (size_t)b * S_ + s;
    float uu = u[row * E_ + e];
    float delta = dlt[row * E_ + e];
    float du = delta * uu;
    const float* bc = dbc + row * 96;
    #pragma unroll
    for (int n = 0; n < N_; ++n) {
      float dA = __expf(delta * A[n]);
      P[n] *= dA;
      h[n] = dA * h[n] + du * bc[64 + n];
    }
  }
  #pragma unroll
  for (int n = 0; n < N_; ++n) {
    size_t off = (size_t)(c * N_ + n) * CH_ + ch;
    Pbuf[off] = P[n];
    Hbuf[off] = h[n];
  }
}

__global__ void k_scan_comb(float* __restrict__ Pbuf, const float* __restrict__ Hbuf) {
  int idx = blockIdx.x * 256 + threadIdx.x;
  int ch = idx & (CH_ - 1);
  int n  = idx >> 12;
  float hcur = 0.f;
  for (int c = 0; c < NC_; ++c) {
    size_t off = (size_t)(c * N_ + n) * CH_ + ch;
    float p  = Pbuf[off];
    float hl = Hbuf[off];
    Pbuf[off] = hcur;
    hcur = p * hcur + hl;
  }
}

template <bool REV>
__global__ void k_scan_apply(float* __restrict__ u, const float* __restrict__ dlt,
                             const float* __restrict__ dbc, const float* __restrict__ Alog,
                             const float* __restrict__ Dp, const float* __restrict__ Pbuf) {
  int ch = (blockIdx.x & 15) * 256 + threadIdx.x;
  int c  = blockIdx.x >> 4;
  int b = ch >> 11, e = ch & (E_ - 1);
  float A[N_], h[N_];
  #pragma unroll
  for (int n = 0; n < N_; ++n) {
    A[n] = -__expf(Alog[(size_t)e * N_ + n]);
    h[n] = Pbuf[(size_t)(c * N_ + n) * CH_ + ch];
  }
  float dp = Dp[e];
  for (int t = 0; t < CS_; ++t) {
    int tau = c * CS_ + t;
    int s = REV ? (S_ - 1 - tau) : tau;
    size_t row = (size_t)b * S_ + s;
    float uu = u[row * E_ + e];
    float delta = dlt[row * E_ + e];
    float du = delta * uu;
    const float* bc = dbc + row * 96;
    float y = 0.f;
    #pragma unroll
    for (int n = 0; n < N_; ++n) {
      float dA = __expf(delta * A[n]);
      h[n] = dA * h[n] + du * bc[64 + n];
      y += h[n] * bc[80 + n];
    }
    u[row * E_ + e] = y + uu * dp;
  }
}

// z1 <- actmx * (z1 + z2)
__global__ void k_ysum(float* __restrict__ z1, const float* __restrict__ z2,
                       const float* __restrict__ amx) {
  size_t i = (size_t)blockIdx.x * 256 + threadIdx.x;
  z1[i] = amx[i] * (z1[i] + z2[i]);
}

extern "C" void kernel_launch(void* const* d_in, const int* in_sizes, int n_in,
                              void* d_out, int out_size, void* d_ws, size_t ws_size,
                              hipStream_t stream) {
  const float* x     = (const float*)d_in[0];
  const float* c     = (const float*)d_in[1];
  const float* n1g   = (const float*)d_in[3];
  const float* n1b   = (const float*)d_in[4];
  const float* n2g   = (const float*)d_in[5];
  const float* n2b   = (const float*)d_in[6];
  const float* Wx    = (const float*)d_in[7];
  const float* bx    = (const float*)d_in[8];
  const float* Wz    = (const float*)d_in[9];
  const float* bz    = (const float*)d_in[10];
  const float* Wf    = (const float*)d_in[11];
  const float* bfb   = (const float*)d_in[12];
  const float* Wada  = (const float*)d_in[13];
  const float* bada  = (const float*)d_in[14];
  const float* Wc1   = (const float*)d_in[15];
  const float* bc1   = (const float*)d_in[16];
  const float* Wc2   = (const float*)d_in[17];
  const float* bc2   = (const float*)d_in[18];
  const float* Wdbc1 = (const float*)d_in[19];
  const float* Wdt1  = (const float*)d_in[20];
  const float* bdt1  = (const float*)d_in[21];
  const float* Alog1 = (const float*)d_in[22];
  const float* Dp1   = (const float*)d_in[23];
  const float* Wdbc2 = (const float*)d_in[24];
  const float* Wdt2  = (const float*)d_in[25];
  const float* bdt2  = (const float*)d_in[26];
  const float* Alog2 = (const float*)d_in[27];
  const float* Dp2   = (const float*)d_in[28];

  const int M = B_ * S_;                 // 2048
  float* ws   = (float*)d_ws;
  float* ada  = ws;                      // 8192
  float* skip = ada + 8192;              // 2,097,152
  float* xs2  = skip + 2097152;          // 2,097,152 (reused: dbc + Hbuf)
  float* mz   = xs2 + 2097152;           // 4,194,304 (reused: Part, then delta)
  float* amx  = mz + 4194304;            // 4,194,304
  float* z1   = amx + 4194304;           // 4,194,304
  float* z2   = z1 + 4194304;            // 4,194,304
  float* dbc  = xs2;                     // alias (xs2 dead after step 3): 196,608
  float* Hbuf = xs2 + 262144;            // alias: 1,048,576
  float* Part = mz;                      // alias (mz dead after step 4): 1,572,864
  float* dlt  = mz;                      // alias (Part dead after reduce): 4,194,304
  float* Pbuf = (float*)d_out;           // scratch; fully overwritten by step 8

  // 1. adaLN params
  k_ada<<<dim3(B_ * 3 * D_), dim3(256), 0, stream>>>(c, Wada, bada, ada);
  // 2. LN1 + modulate + LN2
  k_ln<<<dim3(M), dim3(256), 0, stream>>>(x, n1g, n1b, n2g, n2b, ada, skip, xs2);
  // 3. mz = xs2 @ Wz^T + bz ; actmx = silu(xs2 @ Wx^T + bx)   [MFMA]
  k_mgemm<0><<<dim3(E_ / 128, M / 128), 256, 0, stream>>>(xs2, D_, Wz, bz, mz, E_, D_,
                                                          nullptr, nullptr, nullptr, nullptr);
  k_mgemm<1><<<dim3(E_ / 128, M / 128), 256, 0, stream>>>(xs2, D_, Wx, bx, amx, E_, D_,
                                                          nullptr, nullptr, nullptr, nullptr);
  // 4. z1 = mz @ Wc1^T + bc1 ; z2 = mz @ Wc2^T + bc2   [MFMA]
  k_mgemm<0><<<dim3(E_ / 128, M / 128), 256, 0, stream>>>(mz, E_, Wc1, bc1, z1, E_, E_,
                                                          nullptr, nullptr, nullptr, nullptr);
  k_mgemm<0><<<dim3(E_ / 128, M / 128), 256, 0, stream>>>(mz, E_, Wc2, bc2, z2, E_, E_,
                                                          nullptr, nullptr, nullptr, nullptr);
  // 5. branch 1: dbc (split-K), delta (softplus fused), forward chunked scan
  k_dbc_split<<<dim3(2, M / 64, KSPLIT_), 256, 0, stream>>>(z1, Wdbc1, Part);
  k_dbc_reduce<<<dim3(M * 96 / 256), 256, 0, stream>>>(Part, dbc);
  k_gemm<true><<<dim3(E_ / 64, M / 64), 256, 0, stream>>>(dbc, 96, Wdt1, bdt1, dlt, M, E_, R_);
  k_scan_chunk<false><<<dim3(256), dim3(256), 0, stream>>>(z1, dlt, dbc, Alog1, Pbuf, Hbuf);
  k_scan_comb<<<dim3(256), dim3(256), 0, stream>>>(Pbuf, Hbuf);
  k_scan_apply<false><<<dim3(256), dim3(256), 0, stream>>>(z1, dlt, dbc, Alog1, Dp1, Pbuf);
  // 6. branch 2: dbc (split-K), delta, reverse chunked scan
  k_dbc_split<<<dim3(2, M / 64, KSPLIT_), 256, 0, stream>>>(z2, Wdbc2, Part);
  k_dbc_reduce<<<dim3(M * 96 / 256), 256, 0, stream>>>(Part, dbc);
  k_gemm<true><<<dim3(E_ / 64, M / 64), 256, 0, stream>>>(dbc, 96, Wdt2, bdt2, dlt, M, E_, R_);
  k_scan_chunk<true><<<dim3(256), dim3(256), 0, stream>>>(z2, dlt, dbc, Alog2, Pbuf, Hbuf);
  k_scan_comb<<<dim3(256), dim3(256), 0, stream>>>(Pbuf, Hbuf);
  k_scan_apply<true><<<dim3(256), dim3(256), 0, stream>>>(z2, dlt, dbc, Alog2, Dp2, Pbuf);
  // 7. ysum = actmx*(z1+z2) -> z1
  k_ysum<<<dim3((M * E_) / 256), 256, 0, stream>>>(z1, z2, amx);
  // 8. out = ysum @ Wf^T + bf + skip ; d_out = x + gate*out   [MFMA]
  k_mgemm<2><<<dim3(D_ / 128, M / 128), 256, 0, stream>>>(z1, E_, Wf, bfb, nullptr, D_, E_,
                                                          skip, x, ada, (float*)d_out);
}

// Round 6
// 499.217 us; speedup vs baseline: 8.1148x; 1.2405x over previous
//
#include <hip/hip_runtime.h>
#include <hip/hip_bf16.h>

#define EPSQ 1e-5f
// Problem sizes
#define B_ 2
#define S_ 1024
#define D_ 1024
#define E_ 2048
#define N_ 16
#define R_ 64
// Chunked scan config
#define CS_ 64
#define NC_ 16
#define CH_ 4096
// dbc split-K config
#define KSPLIT_ 8
#define KCH_ 256   // E_/KSPLIT_

typedef float f32x4 __attribute__((ext_vector_type(4)));
typedef short s16x8 __attribute__((ext_vector_type(8)));

static __device__ __forceinline__ short f2bf_s(float f) {
  __hip_bfloat16 h = __float2bfloat16(f);
  return *reinterpret_cast<short*>(&h);
}

static __device__ __forceinline__ s16x8 cvt8(float4 a, float4 b) {
  s16x8 r;
  r[0] = f2bf_s(a.x); r[1] = f2bf_s(a.y); r[2] = f2bf_s(a.z); r[3] = f2bf_s(a.w);
  r[4] = f2bf_s(b.x); r[5] = f2bf_s(b.y); r[6] = f2bf_s(b.z); r[7] = f2bf_s(b.w);
  return r;
}

static __device__ __forceinline__ float block_sum(float v, float* red) {
  int t = threadIdx.x;
  red[t] = v;
  __syncthreads();
  #pragma unroll
  for (int off = 128; off > 0; off >>= 1) {
    if (t < off) red[t] += red[t + off];
    __syncthreads();
  }
  float r = red[0];
  __syncthreads();
  return r;
}

// ada = silu(c) @ Wada^T + bada   -> [B, 3D] fp32
__global__ void k_ada(const float* __restrict__ c, const float* __restrict__ Wada,
                      const float* __restrict__ bada, float* __restrict__ ada) {
  __shared__ float red[256];
  int j = blockIdx.x % (3 * D_);
  int b = blockIdx.x / (3 * D_);
  const float* crow = c + (size_t)b * (2 * D_);
  const float* wrow = Wada + (size_t)j * (2 * D_);
  float acc = 0.f;
  for (int i = threadIdx.x; i < 2 * D_; i += 256) {
    float cv = crow[i];
    float s = cv / (1.f + __expf(-cv));      // silu
    acc += s * wrow[i];
  }
  float tot = block_sum(acc, red);
  if (threadIdx.x == 0) ada[(size_t)b * (3 * D_) + j] = tot + bada[j];
}

// LN1 -> modulate(scale,shift) -> skip ; LN2 -> xs2.  One block per (b,s) row.
__global__ void k_ln(const float* __restrict__ x,
                     const float* __restrict__ g1, const float* __restrict__ b1,
                     const float* __restrict__ g2, const float* __restrict__ b2,
                     const float* __restrict__ ada,
                     float* __restrict__ skip, float* __restrict__ xs2) {
  __shared__ float red[256];
  int row = blockIdx.x;            // b*S + s
  int b = row >> 10;               // S = 1024
  int t = threadIdx.x;
  const float* xr = x + (size_t)row * D_;

  float v[4];
  float4 xv = *(const float4*)(xr + t * 4);
  v[0] = xv.x; v[1] = xv.y; v[2] = xv.z; v[3] = xv.w;

  float s = v[0] + v[1] + v[2] + v[3];
  float mean = block_sum(s, red) * (1.f / D_);
  float q = 0.f;
  #pragma unroll
  for (int i = 0; i < 4; ++i) { float d = v[i] - mean; q += d * d; }
  float var = block_sum(q, red) * (1.f / D_);
  float rstd = rsqrtf(var + EPSQ);

  const float* shf = ada + (size_t)b * (3 * D_);
  const float* scl = shf + D_;
  float s2 = 0.f;
  #pragma unroll
  for (int i = 0; i < 4; ++i) {
    int d = t * 4 + i;
    float xn = (v[i] - mean) * rstd * g1[d] + b1[d];
    float tt = xn * (1.f + scl[d]) + shf[d];
    v[i] = tt;
    s2 += tt;
    skip[(size_t)row * D_ + d] = tt;
  }
  float mean2 = block_sum(s2, red) * (1.f / D_);
  float q2 = 0.f;
  #pragma unroll
  for (int i = 0; i < 4; ++i) { float d = v[i] - mean2; q2 += d * d; }
  float var2 = block_sum(q2, red) * (1.f / D_);
  float rstd2 = rsqrtf(var2 + EPSQ);
  #pragma unroll
  for (int i = 0; i < 4; ++i) {
    int d = t * 4 + i;
    xs2[(size_t)row * D_ + d] = (v[i] - mean2) * rstd2 * g2[d] + b2[d];
  }
}

// ---------------- MFMA GEMM (bf16 via on-the-fly cvt, f32 accum) -------------
template <int EPI>
__global__ __launch_bounds__(256) void k_mgemm(
    const float* __restrict__ A, int lda,
    const float* __restrict__ W, const float* __restrict__ bias,
    float* __restrict__ C, int Nn, int K,
    const float* __restrict__ skip, const float* __restrict__ xin,
    const float* __restrict__ ada, float* __restrict__ obf) {
  __shared__ __align__(16) unsigned short lA[4096];   // 128 rows x 32 k, swizzled
  __shared__ __align__(16) unsigned short lB[4096];
  const int t = threadIdx.x;
  const int lane = t & 63, wid = t >> 6;
  const int wr = wid >> 1, wc = wid & 1;
  const int m0 = blockIdx.y * 128, n0 = blockIdx.x * 128;

  f32x4 acc[4][4];
  #pragma unroll
  for (int m = 0; m < 4; ++m)
    #pragma unroll
    for (int n = 0; n < 4; ++n) acc[m][n] = (f32x4){0.f, 0.f, 0.f, 0.f};

  const int frow = lane & 15, fkg = lane >> 4;
  int aoff[4], boff[4];
  #pragma unroll
  for (int m = 0; m < 4; ++m) {
    int row = wr * 64 + m * 16 + frow;
    aoff[m] = (row * 64 + fkg * 16) ^ ((row & 7) << 4);
  }
  #pragma unroll
  for (int n = 0; n < 4; ++n) {
    int col = wc * 64 + n * 16 + frow;
    boff[n] = (col * 64 + fkg * 16) ^ ((col & 7) << 4);
  }

  const int sr = t >> 2, sk = (t & 3) * 8;
  const int w0 = (sr * 64 + (t & 3) * 16) ^ ((sr & 7) << 4);
  const int w1 = w0 + 4096;   // +64 rows
  const float* pa0 = A + (size_t)(m0 + sr) * lda + sk;
  const float* pa1 = A + (size_t)(m0 + sr + 64) * lda + sk;
  const float* pb0 = W + (size_t)(n0 + sr) * K + sk;
  const float* pb1 = W + (size_t)(n0 + sr + 64) * K + sk;

  float4 a00 = *(const float4*)(pa0);
  float4 a01 = *(const float4*)(pa0 + 4);
  float4 a10 = *(const float4*)(pa1);
  float4 a11 = *(const float4*)(pa1 + 4);
  float4 b00 = *(const float4*)(pb0);
  float4 b01 = *(const float4*)(pb0 + 4);
  float4 b10 = *(const float4*)(pb1);
  float4 b11 = *(const float4*)(pb1 + 4);

  for (int k0 = 0; k0 < K; k0 += 32) {
    __syncthreads();
    *(s16x8*)((char*)lA + w0) = cvt8(a00, a01);
    *(s16x8*)((char*)lA + w1) = cvt8(a10, a11);
    *(s16x8*)((char*)lB + w0) = cvt8(b00, b01);
    *(s16x8*)((char*)lB + w1) = cvt8(b10, b11);
    __syncthreads();
    int kn = k0 + 32;
    if (kn < K) {
      a00 = *(const float4*)(pa0 + kn); a01 = *(const float4*)(pa0 + kn + 4);
      a10 = *(const float4*)(pa1 + kn); a11 = *(const float4*)(pa1 + kn + 4);
      b00 = *(const float4*)(pb0 + kn); b01 = *(const float4*)(pb0 + kn + 4);
      b10 = *(const float4*)(pb1 + kn); b11 = *(const float4*)(pb1 + kn + 4);
    }
    s16x8 af[4], bfr[4];
    #pragma unroll
    for (int m = 0; m < 4; ++m) af[m] = *(const s16x8*)((const char*)lA + aoff[m]);
    #pragma unroll
    for (int n = 0; n < 4; ++n) bfr[n] = *(const s16x8*)((const char*)lB + boff[n]);
    #pragma unroll
    for (int m = 0; m < 4; ++m)
      #pragma unroll
      for (int n = 0; n < 4; ++n)
        acc[m][n] = __builtin_amdgcn_mfma_f32_16x16x32_bf16(af[m], bfr[n], acc[m][n], 0, 0, 0);
  }

  #pragma unroll
  for (int m = 0; m < 4; ++m) {
    int rbase = m0 + wr * 64 + m * 16 + fkg * 4;
    #pragma unroll
    for (int n = 0; n < 4; ++n) {
      int col = n0 + wc * 64 + n * 16 + frow;
      float bv = bias ? bias[col] : 0.f;
      #pragma unroll
      for (int j = 0; j < 4; ++j) {
        int row = rbase + j;
        float v = acc[m][n][j] + bv;
        if constexpr (EPI == 1) { v = v / (1.f + __expf(-v)); }
        if constexpr (EPI == 2) {
          int b = row >> 10;
          float gate = ada[(size_t)b * (3 * D_) + 2 * D_ + col];
          float o = v + skip[(size_t)row * D_ + col];
          obf[(size_t)row * D_ + col] = xin[(size_t)row * D_ + col] + gate * o;
        } else {
          C[(size_t)row * Nn + col] = v;
        }
      }
    }
  }
}

// ---------------- naive fp32 GEMM (dlt: N=2048, K=64) -------------------------
template <bool SP>
__global__ void k_gemm(const float* __restrict__ A, int lda,
                       const float* __restrict__ W, const float* __restrict__ bias,
                       float* __restrict__ C, int M, int Nn, int K) {
  const int BK = 16;
  __shared__ float As[BK][65];
  __shared__ float Bs[BK][65];
  int n0 = blockIdx.x * 64, m0 = blockIdx.y * 64;
  int t = threadIdx.x;
  int tx = t & 15, ty = t >> 4;
  int ar = t >> 2, ac4 = (t & 3) * 4;
  float acc[4][4] = {};

  for (int k0 = 0; k0 < K; k0 += BK) {
    const float* ap = A + (size_t)(m0 + ar) * lda + k0 + ac4;
    float4 av = *(const float4*)ap;
    As[ac4 + 0][ar] = av.x; As[ac4 + 1][ar] = av.y;
    As[ac4 + 2][ar] = av.z; As[ac4 + 3][ar] = av.w;

    int wn = n0 + ar;
    if (wn < Nn) {
      const float* wp = W + (size_t)wn * K + k0 + ac4;
      float4 wv = *(const float4*)wp;
      Bs[ac4 + 0][ar] = wv.x; Bs[ac4 + 1][ar] = wv.y;
      Bs[ac4 + 2][ar] = wv.z; Bs[ac4 + 3][ar] = wv.w;
    } else {
      Bs[ac4 + 0][ar] = 0.f; Bs[ac4 + 1][ar] = 0.f;
      Bs[ac4 + 2][ar] = 0.f; Bs[ac4 + 3][ar] = 0.f;
    }
    __syncthreads();
    #pragma unroll
    for (int kk = 0; kk < BK; ++kk) {
      float a0 = As[kk][ty * 4 + 0], a1 = As[kk][ty * 4 + 1];
      float a2 = As[kk][ty * 4 + 2], a3 = As[kk][ty * 4 + 3];
      float c0 = Bs[kk][tx * 4 + 0], c1 = Bs[kk][tx * 4 + 1];
      float c2 = Bs[kk][tx * 4 + 2], c3 = Bs[kk][tx * 4 + 3];
      acc[0][0] += a0 * c0; acc[0][1] += a0 * c1; acc[0][2] += a0 * c2; acc[0][3] += a0 * c3;
      acc[1][0] += a1 * c0; acc[1][1] += a1 * c1; acc[1][2] += a1 * c2; acc[1][3] += a1 * c3;
      acc[2][0] += a2 * c0; acc[2][1] += a2 * c1; acc[2][2] += a2 * c2; acc[2][3] += a2 * c3;
      acc[3][0] += a3 * c0; acc[3][1] += a3 * c1; acc[3][2] += a3 * c2; acc[3][3] += a3 * c3;
    }
    __syncthreads();
  }

  #pragma unroll
  for (int i = 0; i < 4; ++i) {
    int row = m0 + ty * 4 + i;
    #pragma unroll
    for (int j = 0; j < 4; ++j) {
      int col = n0 + tx * 4 + j;
      if (col >= Nn) continue;
      float v = acc[i][j];
      if (bias) v += bias[col];
      if constexpr (SP) { v = (v > 20.f) ? v : log1pf(__expf(v)); }
      C[(size_t)row * Nn + col] = v;
    }
  }
}

// ---------------- dbc split-K ----------------
__global__ void k_dbc_split(const float* __restrict__ A, const float* __restrict__ W,
                            float* __restrict__ Part) {
  const int BK = 16;
  __shared__ float As[BK][65];
  __shared__ float Bs[BK][65];
  int n0 = blockIdx.x * 64, m0 = blockIdx.y * 64;
  int kbase = blockIdx.z * KCH_;
  int t = threadIdx.x;
  int tx = t & 15, ty = t >> 4;
  int ar = t >> 2, ac4 = (t & 3) * 4;
  float acc[4][4] = {};

  for (int k0 = 0; k0 < KCH_; k0 += BK) {
    const float* ap = A + (size_t)(m0 + ar) * E_ + kbase + k0 + ac4;
    float4 av = *(const float4*)ap;
    As[ac4 + 0][ar] = av.x; As[ac4 + 1][ar] = av.y;
    As[ac4 + 2][ar] = av.z; As[ac4 + 3][ar] = av.w;

    int wn = n0 + ar;
    if (wn < 96) {
      const float* wp = W + (size_t)wn * E_ + kbase + k0 + ac4;
      float4 wv = *(const float4*)wp;
      Bs[ac4 + 0][ar] = wv.x; Bs[ac4 + 1][ar] = wv.y;
      Bs[ac4 + 2][ar] = wv.z; Bs[ac4 + 3][ar] = wv.w;
    } else {
      Bs[ac4 + 0][ar] = 0.f; Bs[ac4 + 1][ar] = 0.f;
      Bs[ac4 + 2][ar] = 0.f; Bs[ac4 + 3][ar] = 0.f;
    }
    __syncthreads();
    #pragma unroll
    for (int kk = 0; kk < BK; ++kk) {
      float a0 = As[kk][ty * 4 + 0], a1 = As[kk][ty * 4 + 1];
      float a2 = As[kk][ty * 4 + 2], a3 = As[kk][ty * 4 + 3];
      float c0 = Bs[kk][tx * 4 + 0], c1 = Bs[kk][tx * 4 + 1];
      float c2 = Bs[kk][tx * 4 + 2], c3 = Bs[kk][tx * 4 + 3];
      acc[0][0] += a0 * c0; acc[0][1] += a0 * c1; acc[0][2] += a0 * c2; acc[0][3] += a0 * c3;
      acc[1][0] += a1 * c0; acc[1][1] += a1 * c1; acc[1][2] += a1 * c2; acc[1][3] += a1 * c3;
      acc[2][0] += a2 * c0; acc[2][1] += a2 * c1; acc[2][2] += a2 * c2; acc[2][3] += a2 * c3;
      acc[3][0] += a3 * c0; acc[3][1] += a3 * c1; acc[3][2] += a3 * c2; acc[3][3] += a3 * c3;
    }
    __syncthreads();
  }

  #pragma unroll
  for (int i = 0; i < 4; ++i) {
    int row = m0 + ty * 4 + i;
    #pragma unroll
    for (int j = 0; j < 4; ++j) {
      int col = n0 + tx * 4 + j;
      if (col < 96)
        Part[(size_t)blockIdx.z * (B_ * S_ * 96) + (size_t)row * 96 + col] = acc[i][j];
    }
  }
}

__global__ void k_dbc_reduce(const float* __restrict__ Part, float* __restrict__ dbc) {
  int i = blockIdx.x * 256 + threadIdx.x;   // < M*96
  float s = 0.f;
  #pragma unroll
  for (int kz = 0; kz < KSPLIT_; ++kz) s += Part[(size_t)kz * (B_ * S_ * 96) + i];
  dbc[i] = s;
}

// ---- Chunked parallel scan (3 passes), 4 lanes per channel (4 states each) ----
// thread map: tid = chl*4 + q ; ch = (blockIdx.x & 63)*64 + chl ; c = blockIdx.x >> 6
// lane q owns states n = q*4 .. q*4+3.  Grid: 16 chunks * 64 ch-groups = 1024 blocks.
template <bool REV>
__global__ void k_scan_chunk(const float* __restrict__ u, const float* __restrict__ dlt,
                             const float* __restrict__ dbc, const float* __restrict__ Alog,
                             float* __restrict__ Pbuf, float* __restrict__ Hbuf) {
  int tid = threadIdx.x;
  int q = tid & 3, chl = tid >> 2;
  int ch = (blockIdx.x & 63) * 64 + chl;
  int c  = blockIdx.x >> 6;
  int b = ch >> 11, e = ch & (E_ - 1);
  int nb = q * 4;
  float A[4], P[4], h[4];
  #pragma unroll
  for (int i = 0; i < 4; ++i) {
    A[i] = -__expf(Alog[(size_t)e * N_ + nb + i]);
    P[i] = 1.f; h[i] = 0.f;
  }
  for (int t = 0; t < CS_; ++t) {
    int tau = c * CS_ + t;
    int s = REV ? (S_ - 1 - tau) : tau;
    size_t row = (size_t)b * S_ + s;
    float uu = u[row * E_ + e];
    float delta = dlt[row * E_ + e];
    float du = delta * uu;
    float4 Bm = *(const float4*)(dbc + row * 96 + 64 + nb);
    const float bmv[4] = {Bm.x, Bm.y, Bm.z, Bm.w};
    #pragma unroll
    for (int i = 0; i < 4; ++i) {
      float dA = __expf(delta * A[i]);
      P[i] *= dA;
      h[i] = dA * h[i] + du * bmv[i];
    }
  }
  #pragma unroll
  for (int i = 0; i < 4; ++i) {
    size_t off = (size_t)(c * N_ + nb + i) * CH_ + ch;
    Pbuf[off] = P[i];
    Hbuf[off] = h[i];
  }
}

__global__ void k_scan_comb(float* __restrict__ Pbuf, const float* __restrict__ Hbuf) {
  int idx = blockIdx.x * 256 + threadIdx.x;
  int ch = idx & (CH_ - 1);
  int n  = idx >> 12;
  float hcur = 0.f;
  for (int c = 0; c < NC_; ++c) {
    size_t off = (size_t)(c * N_ + n) * CH_ + ch;
    float p  = Pbuf[off];
    float hl = Hbuf[off];
    Pbuf[off] = hcur;
    hcur = p * hcur + hl;
  }
}

template <bool REV>
__global__ void k_scan_apply(float* __restrict__ u, const float* __restrict__ dlt,
                             const float* __restrict__ dbc, const float* __restrict__ Alog,
                             const float* __restrict__ Dp, const float* __restrict__ Pbuf) {
  int tid = threadIdx.x;
  int q = tid & 3, chl = tid >> 2;
  int ch = (blockIdx.x & 63) * 64 + chl;
  int c  = blockIdx.x >> 6;
  int b = ch >> 11, e = ch & (E_ - 1);
  int nb = q * 4;
  float A[4], h[4];
  #pragma unroll
  for (int i = 0; i < 4; ++i) {
    A[i] = -__expf(Alog[(size_t)e * N_ + nb + i]);
    h[i] = Pbuf[(size_t)(c * N_ + nb + i) * CH_ + ch];
  }
  float dp = Dp[e];
  for (int t = 0; t < CS_; ++t) {
    int tau = c * CS_ + t;
    int s = REV ? (S_ - 1 - tau) : tau;
    size_t row = (size_t)b * S_ + s;
    float uu = u[row * E_ + e];
    float delta = dlt[row * E_ + e];
    float du = delta * uu;
    float4 Bm = *(const float4*)(dbc + row * 96 + 64 + nb);
    float4 Cm = *(const float4*)(dbc + row * 96 + 80 + nb);
    const float bmv[4] = {Bm.x, Bm.y, Bm.z, Bm.w};
    const float cmv[4] = {Cm.x, Cm.y, Cm.z, Cm.w};
    float y = 0.f;
    #pragma unroll
    for (int i = 0; i < 4; ++i) {
      float dA = __expf(delta * A[i]);
      h[i] = dA * h[i] + du * bmv[i];
      y += h[i] * cmv[i];
    }
    y += __shfl_xor(y, 1);
    y += __shfl_xor(y, 2);
    if (q == 0) u[row * E_ + e] = y + uu * dp;
  }
}

// z1 <- actmx * (z1 + z2)
__global__ void k_ysum(float* __restrict__ z1, const float* __restrict__ z2,
                       const float* __restrict__ amx) {
  size_t i = (size_t)blockIdx.x * 256 + threadIdx.x;
  z1[i] = amx[i] * (z1[i] + z2[i]);
}

extern "C" void kernel_launch(void* const* d_in, const int* in_sizes, int n_in,
                              void* d_out, int out_size, void* d_ws, size_t ws_size,
                              hipStream_t stream) {
  const float* x     = (const float*)d_in[0];
  const float* c     = (const float*)d_in[1];
  const float* n1g   = (const float*)d_in[3];
  const float* n1b   = (const float*)d_in[4];
  const float* n2g   = (const float*)d_in[5];
  const float* n2b   = (const float*)d_in[6];
  const float* Wx    = (const float*)d_in[7];
  const float* bx    = (const float*)d_in[8];
  const float* Wz    = (const float*)d_in[9];
  const float* bz    = (const float*)d_in[10];
  const float* Wf    = (const float*)d_in[11];
  const float* bfb   = (const float*)d_in[12];
  const float* Wada  = (const float*)d_in[13];
  const float* bada  = (const float*)d_in[14];
  const float* Wc1   = (const float*)d_in[15];
  const float* bc1   = (const float*)d_in[16];
  const float* Wc2   = (const float*)d_in[17];
  const float* bc2   = (const float*)d_in[18];
  const float* Wdbc1 = (const float*)d_in[19];
  const float* Wdt1  = (const float*)d_in[20];
  const float* bdt1  = (const float*)d_in[21];
  const float* Alog1 = (const float*)d_in[22];
  const float* Dp1   = (const float*)d_in[23];
  const float* Wdbc2 = (const float*)d_in[24];
  const float* Wdt2  = (const float*)d_in[25];
  const float* bdt2  = (const float*)d_in[26];
  const float* Alog2 = (const float*)d_in[27];
  const float* Dp2   = (const float*)d_in[28];

  const int M = B_ * S_;                 // 2048
  float* ws   = (float*)d_ws;
  float* ada  = ws;                      // 8192
  float* skip = ada + 8192;              // 2,097,152
  float* xs2  = skip + 2097152;          // 2,097,152 (reused: dbc + Hbuf)
  float* mz   = xs2 + 2097152;           // 4,194,304 (reused: Part, then delta)
  float* amx  = mz + 4194304;            // 4,194,304
  float* z1   = amx + 4194304;           // 4,194,304
  float* z2   = z1 + 4194304;            // 4,194,304
  float* dbc  = xs2;                     // alias (xs2 dead after step 3): 196,608
  float* Hbuf = xs2 + 262144;            // alias: 1,048,576
  float* Part = mz;                      // alias (mz dead after step 4): 1,572,864
  float* dlt  = mz;                      // alias (Part dead after reduce): 4,194,304
  float* Pbuf = (float*)d_out;           // scratch; fully overwritten by step 8

  // 1. adaLN params
  k_ada<<<dim3(B_ * 3 * D_), dim3(256), 0, stream>>>(c, Wada, bada, ada);
  // 2. LN1 + modulate + LN2
  k_ln<<<dim3(M), dim3(256), 0, stream>>>(x, n1g, n1b, n2g, n2b, ada, skip, xs2);
  // 3. mz = xs2 @ Wz^T + bz ; actmx = silu(xs2 @ Wx^T + bx)   [MFMA]
  k_mgemm<0><<<dim3(E_ / 128, M / 128), 256, 0, stream>>>(xs2, D_, Wz, bz, mz, E_, D_,
                                                          nullptr, nullptr, nullptr, nullptr);
  k_mgemm<1><<<dim3(E_ / 128, M / 128), 256, 0, stream>>>(xs2, D_, Wx, bx, amx, E_, D_,
                                                          nullptr, nullptr, nullptr, nullptr);
  // 4. z1 = mz @ Wc1^T + bc1 ; z2 = mz @ Wc2^T + bc2   [MFMA]
  k_mgemm<0><<<dim3(E_ / 128, M / 128), 256, 0, stream>>>(mz, E_, Wc1, bc1, z1, E_, E_,
                                                          nullptr, nullptr, nullptr, nullptr);
  k_mgemm<0><<<dim3(E_ / 128, M / 128), 256, 0, stream>>>(mz, E_, Wc2, bc2, z2, E_, E_,
                                                          nullptr, nullptr, nullptr, nullptr);
  // 5. branch 1: dbc (split-K), delta (softplus fused), forward chunked scan
  k_dbc_split<<<dim3(2, M / 64, KSPLIT_), 256, 0, stream>>>(z1, Wdbc1, Part);
  k_dbc_reduce<<<dim3(M * 96 / 256), 256, 0, stream>>>(Part, dbc);
  k_gemm<true><<<dim3(E_ / 64, M / 64), 256, 0, stream>>>(dbc, 96, Wdt1, bdt1, dlt, M, E_, R_);
  k_scan_chunk<false><<<dim3(1024), dim3(256), 0, stream>>>(z1, dlt, dbc, Alog1, Pbuf, Hbuf);
  k_scan_comb<<<dim3(256), dim3(256), 0, stream>>>(Pbuf, Hbuf);
  k_scan_apply<false><<<dim3(1024), dim3(256), 0, stream>>>(z1, dlt, dbc, Alog1, Dp1, Pbuf);
  // 6. branch 2: dbc (split-K), delta, reverse chunked scan
  k_dbc_split<<<dim3(2, M / 64, KSPLIT_), 256, 0, stream>>>(z2, Wdbc2, Part);
  k_dbc_reduce<<<dim3(M * 96 / 256), 256, 0, stream>>>(Part, dbc);
  k_gemm<true><<<dim3(E_ / 64, M / 64), 256, 0, stream>>>(dbc, 96, Wdt2, bdt2, dlt, M, E_, R_);
  k_scan_chunk<true><<<dim3(1024), dim3(256), 0, stream>>>(z2, dlt, dbc, Alog2, Pbuf, Hbuf);
  k_scan_comb<<<dim3(256), dim3(256), 0, stream>>>(Pbuf, Hbuf);
  k_scan_apply<true><<<dim3(1024), dim3(256), 0, stream>>>(z2, dlt, dbc, Alog2, Dp2, Pbuf);
  // 7. ysum = actmx*(z1+z2) -> z1
  k_ysum<<<dim3((M * E_) / 256), 256, 0, stream>>>(z1, z2, amx);
  // 8. out = ysum @ Wf^T + bf + skip ; d_out = x + gate*out   [MFMA]
  k_mgemm<2><<<dim3(D_ / 128, M / 128), 256, 0, stream>>>(z1, E_, Wf, bfb, nullptr, D_, E_,
                                                          skip, x, ada, (float*)d_out);
}

// Round 7
// 394.913 us; speedup vs baseline: 10.2581x; 1.2641x over previous
//
#include <hip/hip_runtime.h>
#include <hip/hip_bf16.h>

#define EPSQ 1e-5f
// Problem sizes
#define B_ 2
#define S_ 1024
#define D_ 1024
#define E_ 2048
#define N_ 16
#define R_ 64
#define M_ 2048
// Chunked scan config
#define CS_ 64
#define NC_ 16
#define CH_ 4096
// dbc split-K config
#define KSPLIT_ 8
#define KCH_ 256
// out-proj split-K
#define KS3_ 4
#define KC3_ 512

typedef float f32x4 __attribute__((ext_vector_type(4)));
typedef short s16x8 __attribute__((ext_vector_type(8)));

static __device__ __forceinline__ short f2bf_s(float f) {
  __hip_bfloat16 h = __float2bfloat16(f);
  return *reinterpret_cast<short*>(&h);
}

static __device__ __forceinline__ s16x8 cvt8(float4 a, float4 b) {
  s16x8 r;
  r[0] = f2bf_s(a.x); r[1] = f2bf_s(a.y); r[2] = f2bf_s(a.z); r[3] = f2bf_s(a.w);
  r[4] = f2bf_s(b.x); r[5] = f2bf_s(b.y); r[6] = f2bf_s(b.z); r[7] = f2bf_s(b.w);
  return r;
}

static __device__ __forceinline__ float block_sum(float v, float* red) {
  int t = threadIdx.x;
  red[t] = v;
  __syncthreads();
  #pragma unroll
  for (int off = 128; off > 0; off >>= 1) {
    if (t < off) red[t] += red[t + off];
    __syncthreads();
  }
  float r = red[0];
  __syncthreads();
  return r;
}

// ada = silu(c) @ Wada^T + bada   -> [B, 3D] fp32
__global__ void k_ada(const float* __restrict__ c, const float* __restrict__ Wada,
                      const float* __restrict__ bada, float* __restrict__ ada) {
  __shared__ float red[256];
  int j = blockIdx.x % (3 * D_);
  int b = blockIdx.x / (3 * D_);
  const float* crow = c + (size_t)b * (2 * D_);
  const float* wrow = Wada + (size_t)j * (2 * D_);
  float acc = 0.f;
  for (int i = threadIdx.x; i < 2 * D_; i += 256) {
    float cv = crow[i];
    float s = cv / (1.f + __expf(-cv));      // silu
    acc += s * wrow[i];
  }
  float tot = block_sum(acc, red);
  if (threadIdx.x == 0) ada[(size_t)b * (3 * D_) + j] = tot + bada[j];
}

// LN1 -> modulate(scale,shift) -> skip ; LN2 -> xs2.  One block per (b,s) row.
__global__ void k_ln(const float* __restrict__ x,
                     const float* __restrict__ g1, const float* __restrict__ b1,
                     const float* __restrict__ g2, const float* __restrict__ b2,
                     const float* __restrict__ ada,
                     float* __restrict__ skip, float* __restrict__ xs2) {
  __shared__ float red[256];
  int row = blockIdx.x;            // b*S + s
  int b = row >> 10;               // S = 1024
  int t = threadIdx.x;
  const float* xr = x + (size_t)row * D_;

  float v[4];
  float4 xv = *(const float4*)(xr + t * 4);
  v[0] = xv.x; v[1] = xv.y; v[2] = xv.z; v[3] = xv.w;

  float s = v[0] + v[1] + v[2] + v[3];
  float mean = block_sum(s, red) * (1.f / D_);
  float q = 0.f;
  #pragma unroll
  for (int i = 0; i < 4; ++i) { float d = v[i] - mean; q += d * d; }
  float var = block_sum(q, red) * (1.f / D_);
  float rstd = rsqrtf(var + EPSQ);

  const float* shf = ada + (size_t)b * (3 * D_);
  const float* scl = shf + D_;
  float s2 = 0.f;
  #pragma unroll
  for (int i = 0; i < 4; ++i) {
    int d = t * 4 + i;
    float xn = (v[i] - mean) * rstd * g1[d] + b1[d];
    float tt = xn * (1.f + scl[d]) + shf[d];
    v[i] = tt;
    s2 += tt;
    skip[(size_t)row * D_ + d] = tt;
  }
  float mean2 = block_sum(s2, red) * (1.f / D_);
  float q2 = 0.f;
  #pragma unroll
  for (int i = 0; i < 4; ++i) { float d = v[i] - mean2; q2 += d * d; }
  float var2 = block_sum(q2, red) * (1.f / D_);
  float rstd2 = rsqrtf(var2 + EPSQ);
  #pragma unroll
  for (int i = 0; i < 4; ++i) {
    int d = t * 4 + i;
    xs2[(size_t)row * D_ + d] = (v[i] - mean2) * rstd2 * g2[d] + b2[d];
  }
}

// ---------------- MFMA GEMM, double-buffered LDS, fused dual-weight ------------
// MODE 0: dual (W0|W1), plain epilogue -> C0 / C1         (z1|z2)
// MODE 1: dual (W0|W1), second half silu -> C0 / C1       (mz | amx)
// MODE 2: split-K partial (grid.z = K-chunk), no bias -> C0 + kz*M*Nh
// Tile 128x128, BK=32, 4 waves (2x2), one barrier per k-step.
template <int MODE>
__global__ __launch_bounds__(256, 2) void k_mgemm(
    const float* __restrict__ A, int lda,
    const float* __restrict__ W0, const float* __restrict__ W1,
    const float* __restrict__ b0, const float* __restrict__ b1,
    float* __restrict__ C0, float* __restrict__ C1, int Nh, int K) {
  __shared__ __align__(16) unsigned short lA[2][4096];
  __shared__ __align__(16) unsigned short lB[2][4096];
  const int t = threadIdx.x;
  const int lane = t & 63, wid = t >> 6;
  const int wr = wid >> 1, wc = wid & 1;
  const int m0 = blockIdx.y * 128, n0 = blockIdx.x * 128;

  const bool second = (MODE != 2) && (n0 >= Nh);
  const float* W = second ? (W1 + (size_t)(n0 - Nh) * K) : (W0 + (size_t)n0 * K);

  int kb = 0, KT = K / 32;
  if constexpr (MODE == 2) { kb = blockIdx.z * KC3_; KT = KC3_ / 32; }

  f32x4 acc[4][4];
  #pragma unroll
  for (int m = 0; m < 4; ++m)
    #pragma unroll
    for (int n = 0; n < 4; ++n) acc[m][n] = (f32x4){0.f, 0.f, 0.f, 0.f};

  // fragment read byte-offsets (within one buffer, swizzled)
  const int frow = lane & 15, fkg = lane >> 4;
  int aoff[4], boff[4];
  #pragma unroll
  for (int m = 0; m < 4; ++m) {
    int row = wr * 64 + m * 16 + frow;
    aoff[m] = (row * 64 + fkg * 16) ^ ((row & 7) << 4);
  }
  #pragma unroll
  for (int n = 0; n < 4; ++n) {
    int col = wc * 64 + n * 16 + frow;
    boff[n] = (col * 64 + fkg * 16) ^ ((col & 7) << 4);
  }

  // staging coords
  const int sr = t >> 2, sk = (t & 3) * 8;
  const int w0 = (sr * 64 + (t & 3) * 16) ^ ((sr & 7) << 4);
  const int w1 = w0 + 4096;   // +64 rows
  const float* pa0 = A + (size_t)(m0 + sr) * lda + kb + sk;
  const float* pa1 = pa0 + (size_t)64 * lda;
  const float* pb0 = W + (size_t)sr * K + kb + sk;
  const float* pb1 = pb0 + (size_t)64 * K;

  // prologue: k-step 0 -> buf0 ; k-step 1 -> regs
  float4 a00 = *(const float4*)(pa0);     float4 a01 = *(const float4*)(pa0 + 4);
  float4 a10 = *(const float4*)(pa1);     float4 a11 = *(const float4*)(pa1 + 4);
  float4 b00 = *(const float4*)(pb0);     float4 b01 = *(const float4*)(pb0 + 4);
  float4 b10 = *(const float4*)(pb1);     float4 b11 = *(const float4*)(pb1 + 4);
  *(s16x8*)((char*)lA[0] + w0) = cvt8(a00, a01);
  *(s16x8*)((char*)lA[0] + w1) = cvt8(a10, a11);
  *(s16x8*)((char*)lB[0] + w0) = cvt8(b00, b01);
  *(s16x8*)((char*)lB[0] + w1) = cvt8(b10, b11);
  a00 = *(const float4*)(pa0 + 32);  a01 = *(const float4*)(pa0 + 36);
  a10 = *(const float4*)(pa1 + 32);  a11 = *(const float4*)(pa1 + 36);
  b00 = *(const float4*)(pb0 + 32);  b01 = *(const float4*)(pb0 + 36);
  b10 = *(const float4*)(pb1 + 32);  b11 = *(const float4*)(pb1 + 36);

  for (int kt = 0; kt < KT; ++kt) {
    __syncthreads();                       // buf[kt&1] ready; prev reads of buf[nxt] done
    const int cur = kt & 1;
    const int nxt = cur ^ 1;
    s16x8 af[4], bfr[4];
    #pragma unroll
    for (int m = 0; m < 4; ++m) af[m] = *(const s16x8*)((const char*)lA[cur] + aoff[m]);
    #pragma unroll
    for (int n = 0; n < 4; ++n) bfr[n] = *(const s16x8*)((const char*)lB[cur] + boff[n]);
    if (kt + 1 < KT) {                     // stage k-step kt+1 into buf[nxt]
      *(s16x8*)((char*)lA[nxt] + w0) = cvt8(a00, a01);
      *(s16x8*)((char*)lA[nxt] + w1) = cvt8(a10, a11);
      *(s16x8*)((char*)lB[nxt] + w0) = cvt8(b00, b01);
      *(s16x8*)((char*)lB[nxt] + w1) = cvt8(b10, b11);
    }
    if (kt + 2 < KT) {                     // issue loads for k-step kt+2
      int kn = (kt + 2) * 32;
      a00 = *(const float4*)(pa0 + kn);  a01 = *(const float4*)(pa0 + kn + 4);
      a10 = *(const float4*)(pa1 + kn);  a11 = *(const float4*)(pa1 + kn + 4);
      b00 = *(const float4*)(pb0 + kn);  b01 = *(const float4*)(pb0 + kn + 4);
      b10 = *(const float4*)(pb1 + kn);  b11 = *(const float4*)(pb1 + kn + 4);
    }
    #pragma unroll
    for (int m = 0; m < 4; ++m)
      #pragma unroll
      for (int n = 0; n < 4; ++n)
        acc[m][n] = __builtin_amdgcn_mfma_f32_16x16x32_bf16(af[m], bfr[n], acc[m][n], 0, 0, 0);
  }

  // epilogue: D layout col = lane&15, row = (lane>>4)*4 + j
  float* C = second ? C1 : C0;
  const float* bias = second ? b1 : b0;
  #pragma unroll
  for (int m = 0; m < 4; ++m) {
    int rbase = m0 + wr * 64 + m * 16 + fkg * 4;
    #pragma unroll
    for (int n = 0; n < 4; ++n) {
      int colL = (n0 - (second ? Nh : 0)) + wc * 64 + n * 16 + frow;
      #pragma unroll
      for (int j = 0; j < 4; ++j) {
        int row = rbase + j;
        float v = acc[m][n][j];
        if constexpr (MODE == 2) {
          C0[(size_t)blockIdx.z * ((size_t)M_ * D_) + (size_t)row * Nh + colL] = v;
        } else {
          v += bias[colL];
          if (MODE == 1 && second) { v = v / (1.f + __expf(-v)); }
          C[(size_t)row * Nh + colL] = v;
        }
      }
    }
  }
}

// out-proj reduce + final epilogue: v = sum_k Part + bf ; o = v + skip ; out = x + gate*o
__global__ void k_out_red(const float* __restrict__ Part, const float* __restrict__ bfb,
                          const float* __restrict__ skip, const float* __restrict__ x,
                          const float* __restrict__ ada, float* __restrict__ out) {
  int i = blockIdx.x * 256 + threadIdx.x;   // float4 index over M*D/4
  const int PL = M_ * D_ / 4;               // plane stride in float4
  int c4 = i & (D_ / 4 - 1);
  int row = i >> 8;                          // D/4 = 256
  int b = row >> 10;
  const f32x4* P = (const f32x4*)Part;
  f32x4 v = P[i];
  #pragma unroll
  for (int kz = 1; kz < KS3_; ++kz) v += P[(size_t)kz * PL + i];
  f32x4 bv = ((const f32x4*)bfb)[c4];
  f32x4 sv = ((const f32x4*)skip)[i];
  f32x4 xv = ((const f32x4*)x)[i];
  f32x4 gv = ((const f32x4*)(ada + (size_t)b * (3 * D_) + 2 * D_))[c4];
  f32x4 o = v + bv + sv;
  ((f32x4*)out)[i] = xv + gv * o;
}

// ---------------- naive fp32 GEMM (dlt: N=2048, K=64) -------------------------
template <bool SP>
__global__ void k_gemm(const float* __restrict__ A, int lda,
                       const float* __restrict__ W, const float* __restrict__ bias,
                       float* __restrict__ C, int M, int Nn, int K) {
  const int BK = 16;
  __shared__ float As[BK][65];
  __shared__ float Bs[BK][65];
  int n0 = blockIdx.x * 64, m0 = blockIdx.y * 64;
  int t = threadIdx.x;
  int tx = t & 15, ty = t >> 4;
  int ar = t >> 2, ac4 = (t & 3) * 4;
  float acc[4][4] = {};

  for (int k0 = 0; k0 < K; k0 += BK) {
    const float* ap = A + (size_t)(m0 + ar) * lda + k0 + ac4;
    float4 av = *(const float4*)ap;
    As[ac4 + 0][ar] = av.x; As[ac4 + 1][ar] = av.y;
    As[ac4 + 2][ar] = av.z; As[ac4 + 3][ar] = av.w;

    int wn = n0 + ar;
    if (wn < Nn) {
      const float* wp = W + (size_t)wn * K + k0 + ac4;
      float4 wv = *(const float4*)wp;
      Bs[ac4 + 0][ar] = wv.x; Bs[ac4 + 1][ar] = wv.y;
      Bs[ac4 + 2][ar] = wv.z; Bs[ac4 + 3][ar] = wv.w;
    } else {
      Bs[ac4 + 0][ar] = 0.f; Bs[ac4 + 1][ar] = 0.f;
      Bs[ac4 + 2][ar] = 0.f; Bs[ac4 + 3][ar] = 0.f;
    }
    __syncthreads();
    #pragma unroll
    for (int kk = 0; kk < BK; ++kk) {
      float a0 = As[kk][ty * 4 + 0], a1 = As[kk][ty * 4 + 1];
      float a2 = As[kk][ty * 4 + 2], a3 = As[kk][ty * 4 + 3];
      float c0 = Bs[kk][tx * 4 + 0], c1 = Bs[kk][tx * 4 + 1];
      float c2 = Bs[kk][tx * 4 + 2], c3 = Bs[kk][tx * 4 + 3];
      acc[0][0] += a0 * c0; acc[0][1] += a0 * c1; acc[0][2] += a0 * c2; acc[0][3] += a0 * c3;
      acc[1][0] += a1 * c0; acc[1][1] += a1 * c1; acc[1][2] += a1 * c2; acc[1][3] += a1 * c3;
      acc[2][0] += a2 * c0; acc[2][1] += a2 * c1; acc[2][2] += a2 * c2; acc[2][3] += a2 * c3;
      acc[3][0] += a3 * c0; acc[3][1] += a3 * c1; acc[3][2] += a3 * c2; acc[3][3] += a3 * c3;
    }
    __syncthreads();
  }

  #pragma unroll
  for (int i = 0; i < 4; ++i) {
    int row = m0 + ty * 4 + i;
    #pragma unroll
    for (int j = 0; j < 4; ++j) {
      int col = n0 + tx * 4 + j;
      if (col >= Nn) continue;
      float v = acc[i][j];
      if (bias) v += bias[col];
      if constexpr (SP) { v = (v > 20.f) ? v : log1pf(__expf(v)); }
      C[(size_t)row * Nn + col] = v;
    }
  }
}

// ---------------- dbc split-K ----------------
__global__ void k_dbc_split(const float* __restrict__ A, const float* __restrict__ W,
                            float* __restrict__ Part) {
  const int BK = 16;
  __shared__ float As[BK][65];
  __shared__ float Bs[BK][65];
  int n0 = blockIdx.x * 64, m0 = blockIdx.y * 64;
  int kbase = blockIdx.z * KCH_;
  int t = threadIdx.x;
  int tx = t & 15, ty = t >> 4;
  int ar = t >> 2, ac4 = (t & 3) * 4;
  float acc[4][4] = {};

  for (int k0 = 0; k0 < KCH_; k0 += BK) {
    const float* ap = A + (size_t)(m0 + ar) * E_ + kbase + k0 + ac4;
    float4 av = *(const float4*)ap;
    As[ac4 + 0][ar] = av.x; As[ac4 + 1][ar] = av.y;
    As[ac4 + 2][ar] = av.z; As[ac4 + 3][ar] = av.w;

    int wn = n0 + ar;
    if (wn < 96) {
      const float* wp = W + (size_t)wn * E_ + kbase + k0 + ac4;
      float4 wv = *(const float4*)wp;
      Bs[ac4 + 0][ar] = wv.x; Bs[ac4 + 1][ar] = wv.y;
      Bs[ac4 + 2][ar] = wv.z; Bs[ac4 + 3][ar] = wv.w;
    } else {
      Bs[ac4 + 0][ar] = 0.f; Bs[ac4 + 1][ar] = 0.f;
      Bs[ac4 + 2][ar] = 0.f; Bs[ac4 + 3][ar] = 0.f;
    }
    __syncthreads();
    #pragma unroll
    for (int kk = 0; kk < BK; ++kk) {
      float a0 = As[kk][ty * 4 + 0], a1 = As[kk][ty * 4 + 1];
      float a2 = As[kk][ty * 4 + 2], a3 = As[kk][ty * 4 + 3];
      float c0 = Bs[kk][tx * 4 + 0], c1 = Bs[kk][tx * 4 + 1];
      float c2 = Bs[kk][tx * 4 + 2], c3 = Bs[kk][tx * 4 + 3];
      acc[0][0] += a0 * c0; acc[0][1] += a0 * c1; acc[0][2] += a0 * c2; acc[0][3] += a0 * c3;
      acc[1][0] += a1 * c0; acc[1][1] += a1 * c1; acc[1][2] += a1 * c2; acc[1][3] += a1 * c3;
      acc[2][0] += a2 * c0; acc[2][1] += a2 * c1; acc[2][2] += a2 * c2; acc[2][3] += a2 * c3;
      acc[3][0] += a3 * c0; acc[3][1] += a3 * c1; acc[3][2] += a3 * c2; acc[3][3] += a3 * c3;
    }
    __syncthreads();
  }

  #pragma unroll
  for (int i = 0; i < 4; ++i) {
    int row = m0 + ty * 4 + i;
    #pragma unroll
    for (int j = 0; j < 4; ++j) {
      int col = n0 + tx * 4 + j;
      if (col < 96)
        Part[(size_t)blockIdx.z * (M_ * 96) + (size_t)row * 96 + col] = acc[i][j];
    }
  }
}

__global__ void k_dbc_reduce(const float* __restrict__ Part, float* __restrict__ dbc) {
  int i = blockIdx.x * 256 + threadIdx.x;   // < M*96
  float s = 0.f;
  #pragma unroll
  for (int kz = 0; kz < KSPLIT_; ++kz) s += Part[(size_t)kz * (M_ * 96) + i];
  dbc[i] = s;
}

// ---- Chunked parallel scan (3 passes), 4 lanes per channel ----
template <bool REV>
__global__ void k_scan_chunk(const float* __restrict__ u, const float* __restrict__ dlt,
                             const float* __restrict__ dbc, const float* __restrict__ Alog,
                             float* __restrict__ Pbuf, float* __restrict__ Hbuf) {
  int tid = threadIdx.x;
  int q = tid & 3, chl = tid >> 2;
  int ch = (blockIdx.x & 63) * 64 + chl;
  int c  = blockIdx.x >> 6;
  int b = ch >> 11, e = ch & (E_ - 1);
  int nb = q * 4;
  float A[4], P[4], h[4];
  #pragma unroll
  for (int i = 0; i < 4; ++i) {
    A[i] = -__expf(Alog[(size_t)e * N_ + nb + i]);
    P[i] = 1.f; h[i] = 0.f;
  }
  for (int t = 0; t < CS_; ++t) {
    int tau = c * CS_ + t;
    int s = REV ? (S_ - 1 - tau) : tau;
    size_t row = (size_t)b * S_ + s;
    float uu = u[row * E_ + e];
    float delta = dlt[row * E_ + e];
    float du = delta * uu;
    float4 Bm = *(const float4*)(dbc + row * 96 + 64 + nb);
    const float bmv[4] = {Bm.x, Bm.y, Bm.z, Bm.w};
    #pragma unroll
    for (int i = 0; i < 4; ++i) {
      float dA = __expf(delta * A[i]);
      P[i] *= dA;
      h[i] = dA * h[i] + du * bmv[i];
    }
  }
  #pragma unroll
  for (int i = 0; i < 4; ++i) {
    size_t off = (size_t)(c * N_ + nb + i) * CH_ + ch;
    Pbuf[off] = P[i];
    Hbuf[off] = h[i];
  }
}

__global__ void k_scan_comb(float* __restrict__ Pbuf, const float* __restrict__ Hbuf) {
  int idx = blockIdx.x * 256 + threadIdx.x;
  int ch = idx & (CH_ - 1);
  int n  = idx >> 12;
  float hcur = 0.f;
  for (int c = 0; c < NC_; ++c) {
    size_t off = (size_t)(c * N_ + n) * CH_ + ch;
    float p  = Pbuf[off];
    float hl = Hbuf[off];
    Pbuf[off] = hcur;
    hcur = p * hcur + hl;
  }
}

template <bool REV>
__global__ void k_scan_apply(float* __restrict__ u, const float* __restrict__ dlt,
                             const float* __restrict__ dbc, const float* __restrict__ Alog,
                             const float* __restrict__ Dp, const float* __restrict__ Pbuf) {
  int tid = threadIdx.x;
  int q = tid & 3, chl = tid >> 2;
  int ch = (blockIdx.x & 63) * 64 + chl;
  int c  = blockIdx.x >> 6;
  int b = ch >> 11, e = ch & (E_ - 1);
  int nb = q * 4;
  float A[4], h[4];
  #pragma unroll
  for (int i = 0; i < 4; ++i) {
    A[i] = -__expf(Alog[(size_t)e * N_ + nb + i]);
    h[i] = Pbuf[(size_t)(c * N_ + nb + i) * CH_ + ch];
  }
  float dp = Dp[e];
  for (int t = 0; t < CS_; ++t) {
    int tau = c * CS_ + t;
    int s = REV ? (S_ - 1 - tau) : tau;
    size_t row = (size_t)b * S_ + s;
    float uu = u[row * E_ + e];
    float delta = dlt[row * E_ + e];
    float du = delta * uu;
    float4 Bm = *(const float4*)(dbc + row * 96 + 64 + nb);
    float4 Cm = *(const float4*)(dbc + row * 96 + 80 + nb);
    const float bmv[4] = {Bm.x, Bm.y, Bm.z, Bm.w};
    const float cmv[4] = {Cm.x, Cm.y, Cm.z, Cm.w};
    float y = 0.f;
    #pragma unroll
    for (int i = 0; i < 4; ++i) {
      float dA = __expf(delta * A[i]);
      h[i] = dA * h[i] + du * bmv[i];
      y += h[i] * cmv[i];
    }
    y += __shfl_xor(y, 1);
    y += __shfl_xor(y, 2);
    if (q == 0) u[row * E_ + e] = y + uu * dp;
  }
}

// z1 <- actmx * (z1 + z2)
__global__ void k_ysum(float* __restrict__ z1, const float* __restrict__ z2,
                       const float* __restrict__ amx) {
  size_t i = (size_t)blockIdx.x * 256 + threadIdx.x;
  z1[i] = amx[i] * (z1[i] + z2[i]);
}

extern "C" void kernel_launch(void* const* d_in, const int* in_sizes, int n_in,
                              void* d_out, int out_size, void* d_ws, size_t ws_size,
                              hipStream_t stream) {
  const float* x     = (const float*)d_in[0];
  const float* c     = (const float*)d_in[1];
  const float* n1g   = (const float*)d_in[3];
  const float* n1b   = (const float*)d_in[4];
  const float* n2g   = (const float*)d_in[5];
  const float* n2b   = (const float*)d_in[6];
  const float* Wx    = (const float*)d_in[7];
  const float* bx    = (const float*)d_in[8];
  const float* Wz    = (const float*)d_in[9];
  const float* bz    = (const float*)d_in[10];
  const float* Wf    = (const float*)d_in[11];
  const float* bfb   = (const float*)d_in[12];
  const float* Wada  = (const float*)d_in[13];
  const float* bada  = (const float*)d_in[14];
  const float* Wc1   = (const float*)d_in[15];
  const float* bc1   = (const float*)d_in[16];
  const float* Wc2   = (const float*)d_in[17];
  const float* bc2   = (const float*)d_in[18];
  const float* Wdbc1 = (const float*)d_in[19];
  const float* Wdt1  = (const float*)d_in[20];
  const float* bdt1  = (const float*)d_in[21];
  const float* Alog1 = (const float*)d_in[22];
  const float* Dp1   = (const float*)d_in[23];
  const float* Wdbc2 = (const float*)d_in[24];
  const float* Wdt2  = (const float*)d_in[25];
  const float* bdt2  = (const float*)d_in[26];
  const float* Alog2 = (const float*)d_in[27];
  const float* Dp2   = (const float*)d_in[28];

  const int M = M_;                      // 2048
  float* ws   = (float*)d_ws;
  float* ada  = ws;                      // 8192
  float* skip = ada + 8192;              // 2,097,152
  float* xs2  = skip + 2097152;          // 2,097,152 (reused: dbc + Hbuf)
  float* mz   = xs2 + 2097152;           // 4,194,304 (reused: Part/dlt, then Part3 lo)
  float* amx  = mz + 4194304;            // 4,194,304 (reused: Part3 hi)
  float* z1   = amx + 4194304;           // 4,194,304
  float* z2   = z1 + 4194304;            // 4,194,304
  float* dbc  = xs2;                     // alias: 196,608
  float* Hbuf = xs2 + 262144;            // alias: 1,048,576
  float* Part = mz;                      // alias: 1,572,864
  float* dlt  = mz;                      // alias: 4,194,304
  float* Part3 = mz;                     // alias: KS3_*M*D = 8M floats (mz+amx slots)
  float* Pbuf = (float*)d_out;           // scratch; fully overwritten at the end

  // 1. adaLN params
  k_ada<<<dim3(B_ * 3 * D_), dim3(256), 0, stream>>>(c, Wada, bada, ada);
  // 2. LN1 + modulate + LN2
  k_ln<<<dim3(M), dim3(256), 0, stream>>>(x, n1g, n1b, n2g, n2b, ada, skip, xs2);
  // 3. fused: [mz | amx] = xs2 @ [Wz | Wx]^T (+bias, silu on amx half)   [MFMA dual]
  k_mgemm<1><<<dim3(2 * E_ / 128, M / 128), 256, 0, stream>>>(
      xs2, D_, Wz, Wx, bz, bx, mz, amx, E_, D_);
  // 4. fused: [z1 | z2] = mz @ [Wc1 | Wc2]^T + bias   [MFMA dual]
  k_mgemm<0><<<dim3(2 * E_ / 128, M / 128), 256, 0, stream>>>(
      mz, E_, Wc1, Wc2, bc1, bc2, z1, z2, E_, E_);
  // 5. branch 1: dbc (split-K), delta (softplus fused), forward chunked scan
  k_dbc_split<<<dim3(2, M / 64, KSPLIT_), 256, 0, stream>>>(z1, Wdbc1, Part);
  k_dbc_reduce<<<dim3(M * 96 / 256), 256, 0, stream>>>(Part, dbc);
  k_gemm<true><<<dim3(E_ / 64, M / 64), 256, 0, stream>>>(dbc, 96, Wdt1, bdt1, dlt, M, E_, R_);
  k_scan_chunk<false><<<dim3(1024), dim3(256), 0, stream>>>(z1, dlt, dbc, Alog1, Pbuf, Hbuf);
  k_scan_comb<<<dim3(256), dim3(256), 0, stream>>>(Pbuf, Hbuf);
  k_scan_apply<false><<<dim3(1024), dim3(256), 0, stream>>>(z1, dlt, dbc, Alog1, Dp1, Pbuf);
  // 6. branch 2: dbc (split-K), delta, reverse chunked scan
  k_dbc_split<<<dim3(2, M / 64, KSPLIT_), 256, 0, stream>>>(z2, Wdbc2, Part);
  k_dbc_reduce<<<dim3(M * 96 / 256), 256, 0, stream>>>(Part, dbc);
  k_gemm<true><<<dim3(E_ / 64, M / 64), 256, 0, stream>>>(dbc, 96, Wdt2, bdt2, dlt, M, E_, R_);
  k_scan_chunk<true><<<dim3(1024), dim3(256), 0, stream>>>(z2, dlt, dbc, Alog2, Pbuf, Hbuf);
  k_scan_comb<<<dim3(256), dim3(256), 0, stream>>>(Pbuf, Hbuf);
  k_scan_apply<true><<<dim3(1024), dim3(256), 0, stream>>>(z2, dlt, dbc, Alog2, Dp2, Pbuf);
  // 7. ysum = actmx*(z1+z2) -> z1
  k_ysum<<<dim3((M * E_) / 256), 256, 0, stream>>>(z1, z2, amx);
  // 8. out-proj split-K partials: Part3[kz] = ysum @ Wf^T (K-chunk 512)   [MFMA]
  k_mgemm<2><<<dim3(D_ / 128, M / 128, KS3_), 256, 0, stream>>>(
      z1, E_, Wf, nullptr, nullptr, nullptr, Part3, nullptr, D_, E_);
  // 9. reduce + bias + skip + gate + residual -> d_out
  k_out_red<<<dim3(M * D_ / 4 / 256), 256, 0, stream>>>(Part3, bfb, skip, x, ada,
                                                        (float*)d_out);
}